// Round 1
// 1717.783 us; speedup vs baseline: 1.0401x; 1.0401x over previous
//
#include <hip/hip_runtime.h>
#include <math.h>

#define EPI   4
#define NCH   2048
#define HH    48
#define HW    2304          // 48*48
#define NU    3
#define STOT  6912          // NU*HW
#define UP    96
#define UPHW  9216
#define UPS   27648
#define K10   10
#define KM_IT 10
#define OUTD  417
#define OUTHW 173889
#define MASK_OFF 1391112    // 8*417*417
#define EPSF  1e-8f
#define SCL   20.0f

// workspace offsets (floats)
#define OFF_PNBG  0          // [4][2048]
#define OFF_PNFG  8192       // [4][2048]
#define OFF_PBF   16384      // [4][2048][2] interleaved (bg,fg)
#define OFF_NORMQ 32768      // [4][2304]
#define OFF_WFG   41984      // [4][3][2304]
#define OFF_WBG   69632      // [4][3][2304]
#define OFF_CENT  97280      // [4][10][2048]
#define OFF_CT12  179200     // [4][2048][12]  centroid transpose, padded
#define OFF_P12   277504     // [4][2048][12]  final protos, padded
#define OFF_C2    375808     // [4][10]
#define OFF_DENP  375848     // [4][27][10]
#define OFF_D0    376928     // [4][10][6912]
#define OFF_AT12  653408     // [4][6912][12]  padded
#define OFF_D0P   985184     // [16][4][10][6912]
#define OFF_NUMP  5408864    // [4][48][10][2048]  (48 strip partials)
#define OFF_OUTS  9341024    // [4][2][2304]
#define OFF_K1P   9359456    // [4][4][8][3][2304]
#define OFF_KHP   10244192   // [4][8][12][2304]
#define ASSIGN_BYTE_OFF 44515712   // 11128928 floats * 4

// numpart tiling
#define NSTRIPS   48         // 16 strips/img * 3 imgs
#define SSTRIP    144        // locs per strip (2304/16)
#define STILE     16         // locs per LDS tile
#define LDSROW    257        // 256 channels + 1 pad (odd stride -> 2-way banks)

__device__ __forceinline__ void blc(int o, double scale, int hi, int& i0, int& i1, float& w) {
    double v = (double)o * scale;
    int a = (int)v;
    i0 = a;
    i1 = (a + 1 < hi) ? a + 1 : hi;
    w = (float)(v - (double)a);
}

__device__ __forceinline__ float blockReduce256(float v, float* red) {
    int t = threadIdx.x;
    red[t] = v; __syncthreads();
    for (int s = 128; s > 0; s >>= 1) {
        if (t < s) red[t] += red[t + s];
        __syncthreads();
    }
    float r = red[0]; __syncthreads();
    return r;
}

// ---------- K0: normalize sprotos -> pn_bg / pn_fg + interleaved pbf ----------
__global__ __launch_bounds__(256) void k_protonorm(const float* __restrict__ sprotos, float* __restrict__ ws) {
    int epi = blockIdx.x >> 1, which = blockIdx.x & 1;
    const float* p = sprotos + (size_t)(epi * 2 + which) * NCH;
    __shared__ float red[256];
    float ss = 0.f;
    for (int c = threadIdx.x; c < NCH; c += 256) { float v = p[c]; ss = fmaf(v, v, ss); }
    float tot = blockReduce256(ss, red);
    float denom = fmaxf(sqrtf(tot), EPSF);
    float* outp = ws + (which ? OFF_PNFG : OFF_PNBG) + (size_t)epi * NCH;
    for (int c = threadIdx.x; c < NCH; c += 256) {
        float v = p[c] / denom;
        outp[c] = v;
        ws[OFF_PBF + ((size_t)epi * NCH + c) * 2 + which] = v;
    }
}

// ---------- K1a: stage-A partials, float4 along loc ----------
__global__ __launch_bounds__(192) void k_stageA_part(const float* __restrict__ qft, const float* __restrict__ un,
                                                     float* __restrict__ ws) {
    int epi = blockIdx.z;
    int img = blockIdx.y >> 3, cc = blockIdx.y & 7;
    int loc = (blockIdx.x * 192 + threadIdx.x) * 4;   // 0..2300
    const float* base = (img == 0) ? (qft + (size_t)epi * NCH * HW)
                                   : (un + (size_t)(epi * NU + img - 1) * NCH * HW);
    int c0 = cc * 256;
    const float* p = base + (size_t)c0 * HW + loc;
    const float2* pbf = (const float2*)(ws + OFF_PBF) + (size_t)epi * NCH + c0;
    float ss[4] = {0,0,0,0}, db[4] = {0,0,0,0}, df[4] = {0,0,0,0};
    for (int i = 0; i < 256; ++i) {
        float4 v = *(const float4*)(p + (size_t)i * HW);
        float2 bf = pbf[i];
        const float* vv = &v.x;
#pragma unroll
        for (int q = 0; q < 4; ++q) {
            float x = vv[q];
            ss[q] = fmaf(x, x, ss[q]);
            db[q] = fmaf(x, bf.x, db[q]);
            df[q] = fmaf(x, bf.y, df[q]);
        }
    }
    float* k1p = ws + OFF_K1P + (((size_t)(epi * 4 + img) * 8 + cc) * 3) * HW;
    *(float4*)(k1p + loc)          = make_float4(ss[0], ss[1], ss[2], ss[3]);
    *(float4*)(k1p + HW + loc)     = make_float4(db[0], db[1], db[2], db[3]);
    *(float4*)(k1p + 2 * HW + loc) = make_float4(df[0], df[1], df[2], df[3]);
}

// ---------- K1b: finish stage A ----------
__global__ __launch_bounds__(256) void k_stageA_fin(float* __restrict__ ws, float* __restrict__ dout) {
    int epi = blockIdx.z, img = blockIdx.y;
    int loc = blockIdx.x * 256 + threadIdx.x;
    float ss = 0.f, db = 0.f, df = 0.f;
    for (int cc = 0; cc < 8; ++cc) {
        const float* k1p = ws + OFF_K1P + (((size_t)(epi * 4 + img) * 8 + cc) * 3) * HW + loc;
        ss += k1p[0]; db += k1p[HW]; df += k1p[2 * HW];
    }
    float denom = fmaxf(sqrtf(ss), EPSF);
    float sb = SCL * (db / denom), sf = SCL * (df / denom);
    float m = fmaxf(sb, sf);
    float eb = expf(sb - m), ef = expf(sf - m);
    float s = eb + ef;
    float hb = rintf(eb / s), hf = rintf(ef / s);
    if (img == 0) {
        dout[MASK_OFF + (size_t)(epi * 2) * HW + loc] = hb;
        dout[MASK_OFF + (size_t)(epi * 2 + 1) * HW + loc] = hf;
        ws[OFF_NORMQ + (size_t)epi * HW + loc] = denom;
    } else {
        ws[OFF_WBG + (size_t)(epi * NU + img - 1) * HW + loc] = hb;
        ws[OFF_WFG + (size_t)(epi * NU + img - 1) * HW + loc] = hf;
    }
}

// ---------- K2: initial centroids ----------
__global__ __launch_bounds__(256) void k_initcent(const float* __restrict__ un, float* __restrict__ ws) {
    const int sn[5] = {0, 0, 1, 2, 2};
    const int syo[5] = {0, 71, 47, 23, 95};
    const int sxo[5] = {0, 95, 95, 95, 95};
    int epi = blockIdx.z, j = blockIdx.y;
    int c = blockIdx.x * 256 + threadIdx.x;
    int n = sn[j], yo = syo[j], xo = sxo[j];
    int y0, y1, x0, x1; float wy, wx;
    blc(yo, 47.0 / 95.0, 47, y0, y1, wy);
    blc(xo, 47.0 / 95.0, 47, x0, x1, wx);
    const float* p = un + ((size_t)(epi * NU + n) * NCH + c) * HW;
    float v00 = p[y0 * HH + x0], v10 = p[y1 * HH + x0];
    float v01 = p[y0 * HH + x1], v11 = p[y1 * HH + x1];
    float t0 = v00 * (1.f - wy) + v10 * wy;
    float t1 = v01 * (1.f - wy) + v11 * wy;
    float val = t0 * (1.f - wx) + t1 * wx;
    float* cent = ws + OFF_CENT + (size_t)epi * K10 * NCH;
    cent[(size_t)j * NCH + c] = val;
    cent[(size_t)(j + 5) * NCH + c] = val;
    float* ct = ws + OFF_CT12 + ((size_t)epi * NCH + c) * 12;
    ct[j] = val; ct[j + 5] = val;
}

#define STEP10(A, VX) \
    A[0]=fmaf(VX,ca.x,A[0]); A[1]=fmaf(VX,ca.y,A[1]); A[2]=fmaf(VX,ca.z,A[2]); A[3]=fmaf(VX,ca.w,A[3]); \
    A[4]=fmaf(VX,cb.x,A[4]); A[5]=fmaf(VX,cb.y,A[5]); A[6]=fmaf(VX,cb.z,A[6]); A[7]=fmaf(VX,cb.w,A[7]); \
    A[8]=fmaf(VX,cd.x,A[8]); A[9]=fmaf(VX,cd.y,A[9]);

// ---------- KA: D0 partials, float4 points + float4 uniform centroids ----------
__global__ __launch_bounds__(192) void k_d0part(const float* __restrict__ un, float* __restrict__ ws) {
    int epi = blockIdx.z, cch = blockIdx.y;      // 16 chunks x 128 c
    int c0 = cch * 128;
    int s = (blockIdx.x * 192 + threadIdx.x) * 4;   // 0..6908
    int n = s / HW, l = s % HW;
    const float* p = un + ((size_t)(epi * NU + n) * NCH + c0) * HW + l;
    const float4* ct = (const float4*)(ws + OFF_CT12 + ((size_t)epi * NCH + c0) * 12);
    float a0[K10], a1[K10], a2[K10], a3[K10];
#pragma unroll
    for (int j = 0; j < K10; ++j) { a0[j]=0.f; a1[j]=0.f; a2[j]=0.f; a3[j]=0.f; }
    for (int cc = 0; cc < 128; ++cc) {
        float4 v = *(const float4*)(p + (size_t)cc * HW);
        float4 ca = ct[cc * 3], cb = ct[cc * 3 + 1], cd = ct[cc * 3 + 2];
        STEP10(a0, v.x) STEP10(a1, v.y) STEP10(a2, v.z) STEP10(a3, v.w)
    }
    float* d0p = ws + OFF_D0P + (size_t)cch * (EPI * K10 * STOT) + (size_t)epi * K10 * STOT;
#pragma unroll
    for (int j = 0; j < K10; ++j)
        *(float4*)(d0p + (size_t)j * STOT + s) = make_float4(a0[j], a1[j], a2[j], a3[j]);
}

// ---------- KA2: reduce D0 partials (float4) + c2 ----------
__global__ __launch_bounds__(256) void k_d0red(float* __restrict__ ws) {
    __shared__ float red[256];
    int bid = blockIdx.x;
    if (bid < 270) {
        int idx4 = bid * 256 + threadIdx.x;     // float4 index < 69120
        const float4* src = (const float4*)(ws + OFF_D0P) + idx4;
        float4 a = make_float4(0.f, 0.f, 0.f, 0.f);
        for (int cc = 0; cc < 16; ++cc) {
            float4 v = src[(size_t)cc * 69120];
            a.x += v.x; a.y += v.y; a.z += v.z; a.w += v.w;
        }
        *((float4*)(ws + OFF_D0) + idx4) = a;
    } else {
        int b = bid - 270;                      // epi*10+j
        const float* cent = ws + OFF_CENT + (size_t)b * NCH;
        float ss = 0.f;
        for (int c = threadIdx.x; c < NCH; c += 256) { float v = cent[c]; ss = fmaf(v, v, ss); }
        float tot = blockReduce256(ss, red);
        if (threadIdx.x == 0) ws[OFF_C2 + b] = tot;
    }
}

// ---------- KC: assignments ----------
__global__ __launch_bounds__(256) void k_assign(const float* __restrict__ ws,
                                                unsigned char* __restrict__ afg,
                                                unsigned char* __restrict__ abg) {
    int epi = blockIdx.y;
    int i = blockIdx.x * 256 + threadIdx.x;     // 0..27647
    int n = i / UPHW, r = i % UPHW, yo = r / UP, xo = r % UP;
    int y0, y1, x0, x1; float wy, wx;
    blc(yo, 47.0 / 95.0, 47, y0, y1, wy);
    blc(xo, 47.0 / 95.0, 47, x0, x1, wx);
    int sb = n * HW;
    int s00 = sb + y0 * HH + x0, s10 = sb + y1 * HH + x0;
    int s01 = sb + y0 * HH + x1, s11 = sb + y1 * HH + x1;
    const float* D0 = ws + OFF_D0 + (size_t)epi * K10 * STOT;
    const float* c2 = ws + OFF_C2 + epi * K10;
    float dots[K10];
#pragma unroll
    for (int j = 0; j < K10; ++j) {
        const float* dj = D0 + (size_t)j * STOT;
        float t0 = dj[s00] * (1.f - wy) + dj[s10] * wy;
        float t1 = dj[s01] * (1.f - wy) + dj[s11] * wy;
        dots[j] = t0 * (1.f - wx) + t1 * wx;
    }
    int bf = 0; float best = fmaf(-2.f, dots[0], c2[0]);
#pragma unroll
    for (int j = 1; j < 5; ++j) { float sc = fmaf(-2.f, dots[j], c2[j]); if (sc < best) { best = sc; bf = j; } }
    int bb = 0; best = fmaf(-2.f, dots[5], c2[5]);
#pragma unroll
    for (int j = 1; j < 5; ++j) { float sc = fmaf(-2.f, dots[5 + j], c2[5 + j]); if (sc < best) { best = sc; bb = j; } }
    afg[(size_t)epi * UPS + i] = (unsigned char)bf;
    abg[(size_t)epi * UPS + i] = (unsigned char)bb;
}

// ---------- KD: gather A^T rows (padded to 12) + block-partial dens ----------
__global__ __launch_bounds__(256) void k_gatherA(float* __restrict__ ws,
                                                 const unsigned char* __restrict__ afg,
                                                 const unsigned char* __restrict__ abg) {
    __shared__ float red2[10][256];
    int epi = blockIdx.y;
    int s = blockIdx.x * 256 + threadIdx.x;     // 0..6911
    int n = s / HW, loc = s % HW, y = loc / HH, x = loc % HH;

    int yov[6]; float wyv[6]; int nyc = 0;
    int xov[6]; float wxv[6]; int nxc = 0;
#pragma unroll 1
    for (int t = 0; t < 6; ++t) { yov[t] = 0; wyv[t] = 0.f; xov[t] = 0; wxv[t] = 0.f; }
    for (int yo = 0; yo < UP; ++yo) {
        double v = (double)yo * (47.0 / 95.0);
        int a = (int)v; int b = (a + 1 < 47) ? a + 1 : 47;
        float w = (float)(v - (double)a);
        float ctr = ((a == y) ? (1.f - w) : 0.f) + ((b == y) ? w : 0.f);
        if (ctr > 0.f && nyc < 6) { yov[nyc] = yo; wyv[nyc] = ctr; ++nyc; }
    }
    for (int xo = 0; xo < UP; ++xo) {
        double v = (double)xo * (47.0 / 95.0);
        int a = (int)v; int b = (a + 1 < 47) ? a + 1 : 47;
        float w = (float)(v - (double)a);
        float ctr = ((a == x) ? (1.f - w) : 0.f) + ((b == x) ? w : 0.f);
        if (ctr > 0.f && nxc < 6) { xov[nxc] = xo; wxv[nxc] = ctr; ++nxc; }
    }
    float Af[5] = {0, 0, 0, 0, 0}, Ab[5] = {0, 0, 0, 0, 0};
    const unsigned char* fa = afg + (size_t)epi * UPS;
    const unsigned char* ba = abg + (size_t)epi * UPS;
    const float* WF = ws + OFF_WFG + (size_t)(epi * NU + n) * HW;
    const float* WB = ws + OFF_WBG + (size_t)(epi * NU + n) * HW;
#pragma unroll
    for (int a = 0; a < 6; ++a) {
#pragma unroll
        for (int b = 0; b < 6; ++b) {
            int yo = yov[a], xo = xov[b];
            int i = n * UPHW + yo * UP + xo;
            float coef = wyv[a] * wxv[b];
            int mi = (yo >> 1) * HH + (xo >> 1);
            float cf = coef * WF[mi], cb = coef * WB[mi];
            int jf = fa[i], jb = ba[i];
#pragma unroll
            for (int j = 0; j < 5; ++j) {
                Af[j] += (jf == j) ? cf : 0.f;
                Ab[j] += (jb == j) ? cb : 0.f;
            }
        }
    }
    float* at = ws + OFF_AT12 + ((size_t)epi * STOT + s) * 12;
#pragma unroll
    for (int j = 0; j < 5; ++j) { at[j] = Af[j]; at[5 + j] = Ab[j]; }
    // block-partial dens (fg j=0..4, bg j=5..9)
    int t = threadIdx.x;
#pragma unroll
    for (int j = 0; j < 5; ++j) { red2[j][t] = Af[j]; red2[5 + j][t] = Ab[j]; }
    __syncthreads();
    for (int st = 128; st > 0; st >>= 1) {
        for (int e = t; e < 10 * st; e += 256) {
            int j = e / st, i2 = e % st;
            red2[j][i2] += red2[j][i2 + st];
        }
        __syncthreads();
    }
    if (t < 10) ws[OFF_DENP + ((size_t)epi * 27 + blockIdx.x) * 10 + t] = red2[t][0];
}

// ---------- KF: num partials, LDS-tiled transpose-consume ----------
// block = (256-channel chunk) x (144-loc strip); stage [16 loc][256 c] tiles
// coalesced from un, read transposed from LDS (stride 257 -> 2-way banks, free).
// AT12 address depends only on s (wave-uniform) -> scalar loads.
__global__ __launch_bounds__(256) void k_numpart(const float* __restrict__ un, float* __restrict__ ws) {
    __shared__ float tile[STILE * LDSROW];      // 16 x 257 floats = 16.4 KB
    int epi = blockIdx.z;
    int strip = blockIdx.y;                     // 0..47
    int c0 = blockIdx.x * 256;                  // 8 chunks
    int n = strip >> 4;
    int loc0 = (strip & 15) * SSTRIP;
    int t = threadIdx.x;
    int cl = t >> 2;                            // 0..63
    int si0 = (t & 3) * 4;                      // 0,4,8,12
    float acc[K10];
#pragma unroll
    for (int j = 0; j < K10; ++j) acc[j] = 0.f;
    const float* ubase = un + ((size_t)(epi * NU + n) * NCH + c0) * HW + loc0;
    const float* atbase = ws + OFF_AT12 + ((size_t)epi * STOT + n * HW + loc0) * 12;
    for (int tt = 0; tt < SSTRIP / STILE; ++tt) {
#pragma unroll
        for (int pass = 0; pass < 4; ++pass) {
            int c = cl + 64 * pass;
            float4 v = *(const float4*)(ubase + (size_t)c * HW + tt * STILE + si0);
            tile[(si0 + 0) * LDSROW + c] = v.x;
            tile[(si0 + 1) * LDSROW + c] = v.y;
            tile[(si0 + 2) * LDSROW + c] = v.z;
            tile[(si0 + 3) * LDSROW + c] = v.w;
        }
        __syncthreads();
#pragma unroll
        for (int si = 0; si < STILE; ++si) {
            float x = tile[si * LDSROW + t];
            const float* at = atbase + (size_t)(tt * STILE + si) * 12;
#pragma unroll
            for (int j = 0; j < K10; ++j) acc[j] = fmaf(x, at[j], acc[j]);
        }
        __syncthreads();
    }
    float* np = ws + OFF_NUMP + ((size_t)(epi * NSTRIPS + strip) * K10) * NCH + c0 + t;
#pragma unroll
    for (int j = 0; j < K10; ++j) np[(size_t)j * NCH] = acc[j];
}

// ---------- KF2: centroid update (den finish + CT12 write) ----------
__global__ __launch_bounds__(256) void k_centup(float* __restrict__ ws) {
    __shared__ float sden;
    int idx = blockIdx.x * 256 + threadIdx.x;   // < 81920
    int epi = idx / (K10 * NCH);
    int r = idx - epi * K10 * NCH;
    int j = r >> 11, c = r & 2047;
    if (threadIdx.x == 0) {
        float d = 0.f;
        for (int b = 0; b < 27; ++b) d += ws[OFF_DENP + ((size_t)epi * 27 + b) * 10 + j];
        sden = d;
    }
    __syncthreads();
    float num = 0.f;
#pragma unroll 8
    for (int sc = 0; sc < NSTRIPS; ++sc)
        num += ws[OFF_NUMP + ((size_t)(epi * NSTRIPS + sc) * K10 + j) * NCH + c];
    float d = sden;
    size_t ci = OFF_CENT + ((size_t)epi * K10 + j) * NCH + c;
    float newv = (d > 0.f) ? num / (d + EPSF) : ws[ci];
    ws[ci] = newv;
    ws[OFF_CT12 + ((size_t)epi * NCH + c) * 12 + j] = newv;
}

// ---------- KG: build normalized 12-proto interleaved matrix ----------
__global__ __launch_bounds__(256) void k_buildP12(float* __restrict__ ws) {
    __shared__ float red[256];
    int b = blockIdx.x;                        // epi*12+r
    int epi = b / 12, r = b % 12;
    const float* src;
    bool copy = false;
    if (r == 0)      { src = ws + OFF_PNBG + (size_t)epi * NCH; copy = true; }
    else if (r < 6)  { src = ws + OFF_CENT + ((size_t)epi * K10 + 4 + r) * NCH; }   // bg_cls j=5..9
    else if (r == 6) { src = ws + OFF_PNFG + (size_t)epi * NCH; copy = true; }
    else             { src = ws + OFF_CENT + ((size_t)epi * K10 + r - 7) * NCH; }   // fg_cls j=0..4
    float denom = 1.f;
    if (!copy) {
        float ss = 0.f;
        for (int c = threadIdx.x; c < NCH; c += 256) { float v = src[c]; ss = fmaf(v, v, ss); }
        float tot = blockReduce256(ss, red);
        denom = fmaxf(sqrtf(tot), EPSF);
    }
    for (int c = threadIdx.x; c < NCH; c += 256)
        ws[OFF_P12 + ((size_t)epi * NCH + c) * 12 + r] = src[c] / denom;
}

#define STEP12(A, VX) \
    A[0]=fmaf(VX,pa.x,A[0]); A[1]=fmaf(VX,pa.y,A[1]); A[2]=fmaf(VX,pa.z,A[2]); A[3]=fmaf(VX,pa.w,A[3]); \
    A[4]=fmaf(VX,pb.x,A[4]); A[5]=fmaf(VX,pb.y,A[5]); A[6]=fmaf(VX,pb.z,A[6]); A[7]=fmaf(VX,pb.w,A[7]); \
    A[8]=fmaf(VX,pc.x,A[8]); A[9]=fmaf(VX,pc.y,A[9]); A[10]=fmaf(VX,pc.z,A[10]); A[11]=fmaf(VX,pc.w,A[11]);

// ---------- KHa: final sims vs 12 protos, float4 points + uniform float4 protos ----------
__global__ __launch_bounds__(192) void k_pred_part(const float* __restrict__ qft, float* __restrict__ ws) {
    int epi = blockIdx.z, cc = blockIdx.y;
    int c0 = cc * 256;
    int loc = (blockIdx.x * 192 + threadIdx.x) * 4;
    const float* q = qft + ((size_t)epi * NCH + c0) * HW + loc;
    const float4* pr = (const float4*)(ws + OFF_P12 + ((size_t)epi * NCH + c0) * 12);
    float a0[12], a1[12], a2[12], a3[12];
#pragma unroll
    for (int r = 0; r < 12; ++r) { a0[r]=0.f; a1[r]=0.f; a2[r]=0.f; a3[r]=0.f; }
    for (int i = 0; i < 256; ++i) {
        float4 v = *(const float4*)(q + (size_t)i * HW);
        float4 pa = pr[i * 3], pb = pr[i * 3 + 1], pc = pr[i * 3 + 2];
        STEP12(a0, v.x) STEP12(a1, v.y) STEP12(a2, v.z) STEP12(a3, v.w)
    }
    float* khp = ws + OFF_KHP + ((size_t)(epi * 8 + cc) * 12) * HW;
#pragma unroll
    for (int r = 0; r < 12; ++r)
        *(float4*)(khp + (size_t)r * HW + loc) = make_float4(a0[r], a1[r], a2[r], a3[r]);
}

// ---------- KHb: reduce, max over protos, softmax ----------
__global__ __launch_bounds__(256) void k_pred_fin(float* __restrict__ ws) {
    int epi = blockIdx.y;
    int loc = blockIdx.x * 256 + threadIdx.x;
    float dot[12];
#pragma unroll
    for (int r = 0; r < 12; ++r) dot[r] = 0.f;
    for (int cc = 0; cc < 8; ++cc) {
        const float* khp = ws + OFF_KHP + ((size_t)(epi * 8 + cc) * 12) * HW + loc;
#pragma unroll
        for (int r = 0; r < 12; ++r) dot[r] += khp[(size_t)r * HW];
    }
    float mb = dot[0];
#pragma unroll
    for (int r = 1; r < 6; ++r) mb = fmaxf(mb, dot[r]);
    float mf = dot[6];
#pragma unroll
    for (int r = 7; r < 12; ++r) mf = fmaxf(mf, dot[r]);
    float denom = ws[OFF_NORMQ + (size_t)epi * HW + loc];
    float sb = SCL * (mb / denom), sf = SCL * (mf / denom);
    float m = fmaxf(sb, sf);
    float eb = expf(sb - m), ef = expf(sf - m);
    float ssum = eb + ef;
    ws[OFF_OUTS + (size_t)(epi * 2) * HW + loc] = eb / ssum;
    ws[OFF_OUTS + (size_t)(epi * 2 + 1) * HW + loc] = ef / ssum;
}

// ---------- KI: bilinear resize 48x48 -> 417x417 ----------
__global__ __launch_bounds__(256) void k_resize(const float* __restrict__ ws, float* __restrict__ dout) {
    int idx = blockIdx.x * 256 + threadIdx.x;
    if (idx >= 8 * OUTHW) return;
    int img = idx / OUTHW, r = idx - img * OUTHW;
    int yo = r / OUTD, xo = r - yo * OUTD;
    int y0, y1, x0, x1; float wy, wx;
    blc(yo, 47.0 / 416.0, 47, y0, y1, wy);
    blc(xo, 47.0 / 416.0, 47, x0, x1, wx);
    const float* src = ws + OFF_OUTS + (size_t)img * HW;
    float t0 = src[y0 * HH + x0] * (1.f - wy) + src[y1 * HH + x0] * wy;
    float t1 = src[y0 * HH + x1] * (1.f - wy) + src[y1 * HH + x1] * wy;
    dout[idx] = t0 * (1.f - wx) + t1 * wx;
}

extern "C" void kernel_launch(void* const* d_in, const int* in_sizes, int n_in,
                              void* d_out, int out_size, void* d_ws, size_t ws_size,
                              hipStream_t stream) {
    const float* sprotos = (const float*)d_in[0];
    const float* qft     = (const float*)d_in[1];
    const float* un      = (const float*)d_in[2];
    float* ws  = (float*)d_ws;
    float* out = (float*)d_out;
    unsigned char* afg = (unsigned char*)d_ws + ASSIGN_BYTE_OFF;
    unsigned char* abg = afg + (size_t)EPI * UPS;

    hipLaunchKernelGGL(k_protonorm, dim3(8), dim3(256), 0, stream, sprotos, ws);
    hipLaunchKernelGGL(k_stageA_part, dim3(3, 32, EPI), dim3(192), 0, stream, qft, un, ws);
    hipLaunchKernelGGL(k_stageA_fin, dim3(9, 4, EPI), dim3(256), 0, stream, ws, out);
    hipLaunchKernelGGL(k_initcent, dim3(8, 5, EPI), dim3(256), 0, stream, un, ws);
    for (int it = 0; it < KM_IT; ++it) {
        hipLaunchKernelGGL(k_d0part, dim3(9, 16, EPI), dim3(192), 0, stream, un, ws);
        hipLaunchKernelGGL(k_d0red, dim3(310), dim3(256), 0, stream, ws);
        hipLaunchKernelGGL(k_assign, dim3(108, EPI), dim3(256), 0, stream, ws, afg, abg);
        hipLaunchKernelGGL(k_gatherA, dim3(27, EPI), dim3(256), 0, stream, ws, afg, abg);
        hipLaunchKernelGGL(k_numpart, dim3(8, NSTRIPS, EPI), dim3(256), 0, stream, un, ws);
        hipLaunchKernelGGL(k_centup, dim3(320), dim3(256), 0, stream, ws);
    }
    hipLaunchKernelGGL(k_buildP12, dim3(48), dim3(256), 0, stream, ws);
    hipLaunchKernelGGL(k_pred_part, dim3(3, 8, EPI), dim3(192), 0, stream, qft, ws);
    hipLaunchKernelGGL(k_pred_fin, dim3(9, EPI), dim3(256), 0, stream, ws);
    hipLaunchKernelGGL(k_resize, dim3(5435), dim3(256), 0, stream, ws, out);
}

// Round 5
// 1639.469 us; speedup vs baseline: 1.0897x; 1.0478x over previous
//
#include <hip/hip_runtime.h>
#include <math.h>

#define EPI   4
#define NCH   2048
#define HH    48
#define HW    2304          // 48*48
#define NU    3
#define STOT  6912          // NU*HW
#define UP    96
#define UPHW  9216
#define UPS   27648
#define K10   10
#define KM_IT 10
#define OUTD  417
#define OUTHW 173889
#define MASK_OFF 1391112    // 8*417*417
#define EPSF  1e-8f
#define SCL   20.0f

// workspace offsets (floats)
#define OFF_PNBG  0          // [4][2048]
#define OFF_PNFG  8192       // [4][2048]
#define OFF_PBF   16384      // [4][2048][2] interleaved (bg,fg)
#define OFF_NORMQ 32768      // [4][2304]
#define OFF_WFG   41984      // [4][3][2304]
#define OFF_WBG   69632      // [4][3][2304]
#define OFF_CENT  97280      // [4][10][2048]
#define OFF_CT12  179200     // [4][2048][12]  centroid transpose, padded
#define OFF_P12   277504     // [4][2048][12]  final protos, padded
#define OFF_C2    375808     // [4][10]
#define OFF_DENP  375848     // [4][27][10]
#define OFF_D0    376928     // [4][10][6912]
#define OFF_AT12  653408     // [4][6912][12]  padded
#define OFF_D0P   985184     // [16][4][10][6912]
#define OFF_NUMP  5408864    // [4][48][10][2048]  (48 strip partials)
#define OFF_OUTS  9341024    // [4][2][2304]
#define OFF_K1P   9359456    // [4][4][8][3][2304]
#define OFF_KHP   10244192   // [4][8][12][2304]
#define ASSIGN_BYTE_OFF 44515712   // 11128928 floats * 4

// numpart tiling
#define NSTRIPS   48         // 16 strips/img * 3 imgs
#define SSTRIP    144        // locs per strip (2304/16)
#define STILE     16         // locs per LDS tile
#define LDSROW    257        // 256 channels + 1 pad (odd stride -> 2-way banks)

__device__ __forceinline__ void blc(int o, double scale, int hi, int& i0, int& i1, float& w) {
    double v = (double)o * scale;
    int a = (int)v;
    i0 = a;
    i1 = (a + 1 < hi) ? a + 1 : hi;
    w = (float)(v - (double)a);
}

__device__ __forceinline__ float blockReduce256(float v, float* red) {
    int t = threadIdx.x;
    red[t] = v; __syncthreads();
    for (int s = 128; s > 0; s >>= 1) {
        if (t < s) red[t] += red[t + s];
        __syncthreads();
    }
    float r = red[0]; __syncthreads();
    return r;
}

// ---------- K0: normalize sprotos -> pn_bg / pn_fg + interleaved pbf ----------
__global__ __launch_bounds__(256) void k_protonorm(const float* __restrict__ sprotos, float* __restrict__ ws) {
    int epi = blockIdx.x >> 1, which = blockIdx.x & 1;
    const float* p = sprotos + (size_t)(epi * 2 + which) * NCH;
    __shared__ float red[256];
    float ss = 0.f;
    for (int c = threadIdx.x; c < NCH; c += 256) { float v = p[c]; ss = fmaf(v, v, ss); }
    float tot = blockReduce256(ss, red);
    float denom = fmaxf(sqrtf(tot), EPSF);
    float* outp = ws + (which ? OFF_PNFG : OFF_PNBG) + (size_t)epi * NCH;
    for (int c = threadIdx.x; c < NCH; c += 256) {
        float v = p[c] / denom;
        outp[c] = v;
        ws[OFF_PBF + ((size_t)epi * NCH + c) * 2 + which] = v;
    }
}

// ---------- K1a: stage-A partials, float4 along loc ----------
__global__ __launch_bounds__(192) void k_stageA_part(const float* __restrict__ qft, const float* __restrict__ un,
                                                     float* __restrict__ ws) {
    int epi = blockIdx.z;
    int img = blockIdx.y >> 3, cc = blockIdx.y & 7;
    int loc = (blockIdx.x * 192 + threadIdx.x) * 4;   // 0..2300
    const float* base = (img == 0) ? (qft + (size_t)epi * NCH * HW)
                                   : (un + (size_t)(epi * NU + img - 1) * NCH * HW);
    int c0 = cc * 256;
    const float* p = base + (size_t)c0 * HW + loc;
    const float2* pbf = (const float2*)(ws + OFF_PBF) + (size_t)epi * NCH + c0;
    float ss[4] = {0,0,0,0}, db[4] = {0,0,0,0}, df[4] = {0,0,0,0};
    for (int i = 0; i < 256; ++i) {
        float4 v = *(const float4*)(p + (size_t)i * HW);
        float2 bf = pbf[i];
        const float* vv = &v.x;
#pragma unroll
        for (int q = 0; q < 4; ++q) {
            float x = vv[q];
            ss[q] = fmaf(x, x, ss[q]);
            db[q] = fmaf(x, bf.x, db[q]);
            df[q] = fmaf(x, bf.y, df[q]);
        }
    }
    float* k1p = ws + OFF_K1P + (((size_t)(epi * 4 + img) * 8 + cc) * 3) * HW;
    *(float4*)(k1p + loc)          = make_float4(ss[0], ss[1], ss[2], ss[3]);
    *(float4*)(k1p + HW + loc)     = make_float4(db[0], db[1], db[2], db[3]);
    *(float4*)(k1p + 2 * HW + loc) = make_float4(df[0], df[1], df[2], df[3]);
}

// ---------- K1b: finish stage A ----------
__global__ __launch_bounds__(256) void k_stageA_fin(float* __restrict__ ws, float* __restrict__ dout) {
    int epi = blockIdx.z, img = blockIdx.y;
    int loc = blockIdx.x * 256 + threadIdx.x;
    float ss = 0.f, db = 0.f, df = 0.f;
    for (int cc = 0; cc < 8; ++cc) {
        const float* k1p = ws + OFF_K1P + (((size_t)(epi * 4 + img) * 8 + cc) * 3) * HW + loc;
        ss += k1p[0]; db += k1p[HW]; df += k1p[2 * HW];
    }
    float denom = fmaxf(sqrtf(ss), EPSF);
    float sb = SCL * (db / denom), sf = SCL * (df / denom);
    float m = fmaxf(sb, sf);
    float eb = expf(sb - m), ef = expf(sf - m);
    float s = eb + ef;
    float hb = rintf(eb / s), hf = rintf(ef / s);
    if (img == 0) {
        dout[MASK_OFF + (size_t)(epi * 2) * HW + loc] = hb;
        dout[MASK_OFF + (size_t)(epi * 2 + 1) * HW + loc] = hf;
        ws[OFF_NORMQ + (size_t)epi * HW + loc] = denom;
    } else {
        ws[OFF_WBG + (size_t)(epi * NU + img - 1) * HW + loc] = hb;
        ws[OFF_WFG + (size_t)(epi * NU + img - 1) * HW + loc] = hf;
    }
}

// ---------- K2: initial centroids ----------
__global__ __launch_bounds__(256) void k_initcent(const float* __restrict__ un, float* __restrict__ ws) {
    const int sn[5] = {0, 0, 1, 2, 2};
    const int syo[5] = {0, 71, 47, 23, 95};
    const int sxo[5] = {0, 95, 95, 95, 95};
    int epi = blockIdx.z, j = blockIdx.y;
    int c = blockIdx.x * 256 + threadIdx.x;
    int n = sn[j], yo = syo[j], xo = sxo[j];
    int y0, y1, x0, x1; float wy, wx;
    blc(yo, 47.0 / 95.0, 47, y0, y1, wy);
    blc(xo, 47.0 / 95.0, 47, x0, x1, wx);
    const float* p = un + ((size_t)(epi * NU + n) * NCH + c) * HW;
    float v00 = p[y0 * HH + x0], v10 = p[y1 * HH + x0];
    float v01 = p[y0 * HH + x1], v11 = p[y1 * HH + x1];
    float t0 = v00 * (1.f - wy) + v10 * wy;
    float t1 = v01 * (1.f - wy) + v11 * wy;
    float val = t0 * (1.f - wx) + t1 * wx;
    float* cent = ws + OFF_CENT + (size_t)epi * K10 * NCH;
    cent[(size_t)j * NCH + c] = val;
    cent[(size_t)(j + 5) * NCH + c] = val;
    float* ct = ws + OFF_CT12 + ((size_t)epi * NCH + c) * 12;
    ct[j] = val; ct[j + 5] = val;
}

#define STEP10(A, VX) \
    A[0]=fmaf(VX,ca.x,A[0]); A[1]=fmaf(VX,ca.y,A[1]); A[2]=fmaf(VX,ca.z,A[2]); A[3]=fmaf(VX,ca.w,A[3]); \
    A[4]=fmaf(VX,cb.x,A[4]); A[5]=fmaf(VX,cb.y,A[5]); A[6]=fmaf(VX,cb.z,A[6]); A[7]=fmaf(VX,cb.w,A[7]); \
    A[8]=fmaf(VX,cd.x,A[8]); A[9]=fmaf(VX,cd.y,A[9]);

// ---------- KA: D0 partials, float2 points (2 locs/thread, 2x blocks for occupancy) ----------
// Per-(loc,j) fmaf chain over cc identical to the verified float4 version -> bit-exact.
__global__ __launch_bounds__(192) void k_d0part(const float* __restrict__ un, float* __restrict__ ws) {
    int epi = blockIdx.z, cch = blockIdx.y;      // 16 chunks x 128 c
    int c0 = cch * 128;
    int s = (blockIdx.x * 192 + threadIdx.x) * 2;   // 0..6910 (grid.x = 18)
    int n = s / HW, l = s % HW;
    const float* p = un + ((size_t)(epi * NU + n) * NCH + c0) * HW + l;
    const float4* ct = (const float4*)(ws + OFF_CT12 + ((size_t)epi * NCH + c0) * 12);
    float a0[K10], a1[K10];
#pragma unroll
    for (int j = 0; j < K10; ++j) { a0[j]=0.f; a1[j]=0.f; }
    for (int cc = 0; cc < 128; ++cc) {
        float2 v = *(const float2*)(p + (size_t)cc * HW);
        float4 ca = ct[cc * 3], cb = ct[cc * 3 + 1], cd = ct[cc * 3 + 2];
        STEP10(a0, v.x) STEP10(a1, v.y)
    }
    float* d0p = ws + OFF_D0P + (size_t)cch * (EPI * K10 * STOT) + (size_t)epi * K10 * STOT;
#pragma unroll
    for (int j = 0; j < K10; ++j)
        *(float2*)(d0p + (size_t)j * STOT + s) = make_float2(a0[j], a1[j]);
}

// ---------- KA2: reduce D0 partials (float4) + c2 ----------
__global__ __launch_bounds__(256) void k_d0red(float* __restrict__ ws) {
    __shared__ float red[256];
    int bid = blockIdx.x;
    if (bid < 270) {
        int idx4 = bid * 256 + threadIdx.x;     // float4 index < 69120
        const float4* src = (const float4*)(ws + OFF_D0P) + idx4;
        float4 a = make_float4(0.f, 0.f, 0.f, 0.f);
        for (int cc = 0; cc < 16; ++cc) {
            float4 v = src[(size_t)cc * 69120];
            a.x += v.x; a.y += v.y; a.z += v.z; a.w += v.w;
        }
        *((float4*)(ws + OFF_D0) + idx4) = a;
    } else {
        int b = bid - 270;                      // epi*10+j
        const float* cent = ws + OFF_CENT + (size_t)b * NCH;
        float ss = 0.f;
        for (int c = threadIdx.x; c < NCH; c += 256) { float v = cent[c]; ss = fmaf(v, v, ss); }
        float tot = blockReduce256(ss, red);
        if (threadIdx.x == 0) ws[OFF_C2 + b] = tot;
    }
}

// ---------- KC: assignments (64-thr blocks spread across all CUs; per-thread work unchanged) ----------
__global__ __launch_bounds__(64) void k_assign(const float* __restrict__ ws,
                                               unsigned char* __restrict__ afg,
                                               unsigned char* __restrict__ abg) {
    int epi = blockIdx.y;
    int i = blockIdx.x * 64 + threadIdx.x;      // 0..27647 (grid.x = 432)
    int n = i / UPHW, r = i % UPHW, yo = r / UP, xo = r % UP;
    int y0, y1, x0, x1; float wy, wx;
    blc(yo, 47.0 / 95.0, 47, y0, y1, wy);
    blc(xo, 47.0 / 95.0, 47, x0, x1, wx);
    int sb = n * HW;
    int s00 = sb + y0 * HH + x0, s10 = sb + y1 * HH + x0;
    int s01 = sb + y0 * HH + x1, s11 = sb + y1 * HH + x1;
    const float* D0 = ws + OFF_D0 + (size_t)epi * K10 * STOT;
    const float* c2 = ws + OFF_C2 + epi * K10;
    float dots[K10];
#pragma unroll
    for (int j = 0; j < K10; ++j) {
        const float* dj = D0 + (size_t)j * STOT;
        float t0 = dj[s00] * (1.f - wy) + dj[s10] * wy;
        float t1 = dj[s01] * (1.f - wy) + dj[s11] * wy;
        dots[j] = t0 * (1.f - wx) + t1 * wx;
    }
    int bf = 0; float best = fmaf(-2.f, dots[0], c2[0]);
#pragma unroll
    for (int j = 1; j < 5; ++j) { float sc = fmaf(-2.f, dots[j], c2[j]); if (sc < best) { best = sc; bf = j; } }
    int bb = 0; best = fmaf(-2.f, dots[5], c2[5]);
#pragma unroll
    for (int j = 1; j < 5; ++j) { float sc = fmaf(-2.f, dots[5 + j], c2[5 + j]); if (sc < best) { best = sc; bb = j; } }
    afg[(size_t)epi * UPS + i] = (unsigned char)bf;
    abg[(size_t)epi * UPS + i] = (unsigned char)bb;
}

// ---------- KD: gather A^T rows (padded to 12) + block-partial dens ----------
__global__ __launch_bounds__(256) void k_gatherA(float* __restrict__ ws,
                                                 const unsigned char* __restrict__ afg,
                                                 const unsigned char* __restrict__ abg) {
    __shared__ float red2[10][256];
    int epi = blockIdx.y;
    int s = blockIdx.x * 256 + threadIdx.x;     // 0..6911
    int n = s / HW, loc = s % HW, y = loc / HH, x = loc % HH;

    int yov[6]; float wyv[6]; int nyc = 0;
    int xov[6]; float wxv[6]; int nxc = 0;
#pragma unroll 1
    for (int t = 0; t < 6; ++t) { yov[t] = 0; wyv[t] = 0.f; xov[t] = 0; wxv[t] = 0.f; }
    for (int yo = 0; yo < UP; ++yo) {
        double v = (double)yo * (47.0 / 95.0);
        int a = (int)v; int b = (a + 1 < 47) ? a + 1 : 47;
        float w = (float)(v - (double)a);
        float ctr = ((a == y) ? (1.f - w) : 0.f) + ((b == y) ? w : 0.f);
        if (ctr > 0.f && nyc < 6) { yov[nyc] = yo; wyv[nyc] = ctr; ++nyc; }
    }
    for (int xo = 0; xo < UP; ++xo) {
        double v = (double)xo * (47.0 / 95.0);
        int a = (int)v; int b = (a + 1 < 47) ? a + 1 : 47;
        float w = (float)(v - (double)a);
        float ctr = ((a == x) ? (1.f - w) : 0.f) + ((b == x) ? w : 0.f);
        if (ctr > 0.f && nxc < 6) { xov[nxc] = xo; wxv[nxc] = ctr; ++nxc; }
    }
    float Af[5] = {0, 0, 0, 0, 0}, Ab[5] = {0, 0, 0, 0, 0};
    const unsigned char* fa = afg + (size_t)epi * UPS;
    const unsigned char* ba = abg + (size_t)epi * UPS;
    const float* WF = ws + OFF_WFG + (size_t)(epi * NU + n) * HW;
    const float* WB = ws + OFF_WBG + (size_t)(epi * NU + n) * HW;
#pragma unroll
    for (int a = 0; a < 6; ++a) {
#pragma unroll
        for (int b = 0; b < 6; ++b) {
            int yo = yov[a], xo = xov[b];
            int i = n * UPHW + yo * UP + xo;
            float coef = wyv[a] * wxv[b];
            int mi = (yo >> 1) * HH + (xo >> 1);
            float cf = coef * WF[mi], cb = coef * WB[mi];
            int jf = fa[i], jb = ba[i];
#pragma unroll
            for (int j = 0; j < 5; ++j) {
                Af[j] += (jf == j) ? cf : 0.f;
                Ab[j] += (jb == j) ? cb : 0.f;
            }
        }
    }
    float* at = ws + OFF_AT12 + ((size_t)epi * STOT + s) * 12;
#pragma unroll
    for (int j = 0; j < 5; ++j) { at[j] = Af[j]; at[5 + j] = Ab[j]; }
    // block-partial dens (fg j=0..4, bg j=5..9)
    int t = threadIdx.x;
#pragma unroll
    for (int j = 0; j < 5; ++j) { red2[j][t] = Af[j]; red2[5 + j][t] = Ab[j]; }
    __syncthreads();
    for (int st = 128; st > 0; st >>= 1) {
        for (int e = t; e < 10 * st; e += 256) {
            int j = e / st, i2 = e % st;
            red2[j][i2] += red2[j][i2 + st];
        }
        __syncthreads();
    }
    if (t < 10) ws[OFF_DENP + ((size_t)epi * 27 + blockIdx.x) * 10 + t] = red2[t][0];
}

// ---------- KF: num partials, LDS-tiled transpose-consume ----------
__global__ __launch_bounds__(256) void k_numpart(const float* __restrict__ un, float* __restrict__ ws) {
    __shared__ float tile[STILE * LDSROW];      // 16 x 257 floats = 16.4 KB
    int epi = blockIdx.z;
    int strip = blockIdx.y;                     // 0..47
    int c0 = blockIdx.x * 256;                  // 8 chunks
    int n = strip >> 4;
    int loc0 = (strip & 15) * SSTRIP;
    int t = threadIdx.x;
    int cl = t >> 2;                            // 0..63
    int si0 = (t & 3) * 4;                      // 0,4,8,12
    float acc[K10];
#pragma unroll
    for (int j = 0; j < K10; ++j) acc[j] = 0.f;
    const float* ubase = un + ((size_t)(epi * NU + n) * NCH + c0) * HW + loc0;
    const float* atbase = ws + OFF_AT12 + ((size_t)epi * STOT + n * HW + loc0) * 12;
    for (int tt = 0; tt < SSTRIP / STILE; ++tt) {
#pragma unroll
        for (int pass = 0; pass < 4; ++pass) {
            int c = cl + 64 * pass;
            float4 v = *(const float4*)(ubase + (size_t)c * HW + tt * STILE + si0);
            tile[(si0 + 0) * LDSROW + c] = v.x;
            tile[(si0 + 1) * LDSROW + c] = v.y;
            tile[(si0 + 2) * LDSROW + c] = v.z;
            tile[(si0 + 3) * LDSROW + c] = v.w;
        }
        __syncthreads();
#pragma unroll
        for (int si = 0; si < STILE; ++si) {
            float x = tile[si * LDSROW + t];
            const float* at = atbase + (size_t)(tt * STILE + si) * 12;
#pragma unroll
            for (int j = 0; j < K10; ++j) acc[j] = fmaf(x, at[j], acc[j]);
        }
        __syncthreads();
    }
    float* np = ws + OFF_NUMP + ((size_t)(epi * NSTRIPS + strip) * K10) * NCH + c0 + t;
#pragma unroll
    for (int j = 0; j < K10; ++j) np[(size_t)j * NCH] = acc[j];
}

// ---------- KF2: centroid update (den finish + CT12 write) ----------
__global__ __launch_bounds__(256) void k_centup(float* __restrict__ ws) {
    __shared__ float sden;
    int idx = blockIdx.x * 256 + threadIdx.x;   // < 81920
    int epi = idx / (K10 * NCH);
    int r = idx - epi * K10 * NCH;
    int j = r >> 11, c = r & 2047;
    if (threadIdx.x == 0) {
        float d = 0.f;
        for (int b = 0; b < 27; ++b) d += ws[OFF_DENP + ((size_t)epi * 27 + b) * 10 + j];
        sden = d;
    }
    __syncthreads();
    float num = 0.f;
#pragma unroll 8
    for (int sc = 0; sc < NSTRIPS; ++sc)
        num += ws[OFF_NUMP + ((size_t)(epi * NSTRIPS + sc) * K10 + j) * NCH + c];
    float d = sden;
    size_t ci = OFF_CENT + ((size_t)epi * K10 + j) * NCH + c;
    float newv = (d > 0.f) ? num / (d + EPSF) : ws[ci];
    ws[ci] = newv;
    ws[OFF_CT12 + ((size_t)epi * NCH + c) * 12 + j] = newv;
}

// ---------- KG: build normalized 12-proto interleaved matrix ----------
__global__ __launch_bounds__(256) void k_buildP12(float* __restrict__ ws) {
    __shared__ float red[256];
    int b = blockIdx.x;                        // epi*12+r
    int epi = b / 12, r = b % 12;
    const float* src;
    bool copy = false;
    if (r == 0)      { src = ws + OFF_PNBG + (size_t)epi * NCH; copy = true; }
    else if (r < 6)  { src = ws + OFF_CENT + ((size_t)epi * K10 + 4 + r) * NCH; }   // bg_cls j=5..9
    else if (r == 6) { src = ws + OFF_PNFG + (size_t)epi * NCH; copy = true; }
    else             { src = ws + OFF_CENT + ((size_t)epi * K10 + r - 7) * NCH; }   // fg_cls j=0..4
    float denom = 1.f;
    if (!copy) {
        float ss = 0.f;
        for (int c = threadIdx.x; c < NCH; c += 256) { float v = src[c]; ss = fmaf(v, v, ss); }
        float tot = blockReduce256(ss, red);
        denom = fmaxf(sqrtf(tot), EPSF);
    }
    for (int c = threadIdx.x; c < NCH; c += 256)
        ws[OFF_P12 + ((size_t)epi * NCH + c) * 12 + r] = src[c] / denom;
}

#define STEP12(A, VX) \
    A[0]=fmaf(VX,pa.x,A[0]); A[1]=fmaf(VX,pa.y,A[1]); A[2]=fmaf(VX,pa.z,A[2]); A[3]=fmaf(VX,pa.w,A[3]); \
    A[4]=fmaf(VX,pb.x,A[4]); A[5]=fmaf(VX,pb.y,A[5]); A[6]=fmaf(VX,pb.z,A[6]); A[7]=fmaf(VX,pb.w,A[7]); \
    A[8]=fmaf(VX,pc.x,A[8]); A[9]=fmaf(VX,pc.y,A[9]); A[10]=fmaf(VX,pc.z,A[10]); A[11]=fmaf(VX,pc.w,A[11]);

// ---------- KHa: final sims vs 12 protos, float4 points + uniform float4 protos ----------
__global__ __launch_bounds__(192) void k_pred_part(const float* __restrict__ qft, float* __restrict__ ws) {
    int epi = blockIdx.z, cc = blockIdx.y;
    int c0 = cc * 256;
    int loc = (blockIdx.x * 192 + threadIdx.x) * 4;
    const float* q = qft + ((size_t)epi * NCH + c0) * HW + loc;
    const float4* pr = (const float4*)(ws + OFF_P12 + ((size_t)epi * NCH + c0) * 12);
    float a0[12], a1[12], a2[12], a3[12];
#pragma unroll
    for (int r = 0; r < 12; ++r) { a0[r]=0.f; a1[r]=0.f; a2[r]=0.f; a3[r]=0.f; }
    for (int i = 0; i < 256; ++i) {
        float4 v = *(const float4*)(q + (size_t)i * HW);
        float4 pa = pr[i * 3], pb = pr[i * 3 + 1], pc = pr[i * 3 + 2];
        STEP12(a0, v.x) STEP12(a1, v.y) STEP12(a2, v.z) STEP12(a3, v.w)
    }
    float* khp = ws + OFF_KHP + ((size_t)(epi * 8 + cc) * 12) * HW;
#pragma unroll
    for (int r = 0; r < 12; ++r)
        *(float4*)(khp + (size_t)r * HW + loc) = make_float4(a0[r], a1[r], a2[r], a3[r]);
}

// ---------- KHb: reduce, max over protos, softmax ----------
__global__ __launch_bounds__(256) void k_pred_fin(float* __restrict__ ws) {
    int epi = blockIdx.y;
    int loc = blockIdx.x * 256 + threadIdx.x;
    float dot[12];
#pragma unroll
    for (int r = 0; r < 12; ++r) dot[r] = 0.f;
    for (int cc = 0; cc < 8; ++cc) {
        const float* khp = ws + OFF_KHP + ((size_t)(epi * 8 + cc) * 12) * HW + loc;
#pragma unroll
        for (int r = 0; r < 12; ++r) dot[r] += khp[(size_t)r * HW];
    }
    float mb = dot[0];
#pragma unroll
    for (int r = 1; r < 6; ++r) mb = fmaxf(mb, dot[r]);
    float mf = dot[6];
#pragma unroll
    for (int r = 7; r < 12; ++r) mf = fmaxf(mf, dot[r]);
    float denom = ws[OFF_NORMQ + (size_t)epi * HW + loc];
    float sb = SCL * (mb / denom), sf = SCL * (mf / denom);
    float m = fmaxf(sb, sf);
    float eb = expf(sb - m), ef = expf(sf - m);
    float ssum = eb + ef;
    ws[OFF_OUTS + (size_t)(epi * 2) * HW + loc] = eb / ssum;
    ws[OFF_OUTS + (size_t)(epi * 2 + 1) * HW + loc] = ef / ssum;
}

// ---------- KI: bilinear resize 48x48 -> 417x417 ----------
__global__ __launch_bounds__(256) void k_resize(const float* __restrict__ ws, float* __restrict__ dout) {
    int idx = blockIdx.x * 256 + threadIdx.x;
    if (idx >= 8 * OUTHW) return;
    int img = idx / OUTHW, r = idx - img * OUTHW;
    int yo = r / OUTD, xo = r - yo * OUTD;
    int y0, y1, x0, x1; float wy, wx;
    blc(yo, 47.0 / 416.0, 47, y0, y1, wy);
    blc(xo, 47.0 / 416.0, 47, x0, x1, wx);
    const float* src = ws + OFF_OUTS + (size_t)img * HW;
    float t0 = src[y0 * HH + x0] * (1.f - wy) + src[y1 * HH + x0] * wy;
    float t1 = src[y0 * HH + x1] * (1.f - wy) + src[y1 * HH + x1] * wy;
    dout[idx] = t0 * (1.f - wx) + t1 * wx;
}

extern "C" void kernel_launch(void* const* d_in, const int* in_sizes, int n_in,
                              void* d_out, int out_size, void* d_ws, size_t ws_size,
                              hipStream_t stream) {
    const float* sprotos = (const float*)d_in[0];
    const float* qft     = (const float*)d_in[1];
    const float* un      = (const float*)d_in[2];
    float* ws  = (float*)d_ws;
    float* out = (float*)d_out;
    unsigned char* afg = (unsigned char*)d_ws + ASSIGN_BYTE_OFF;
    unsigned char* abg = afg + (size_t)EPI * UPS;

    hipLaunchKernelGGL(k_protonorm, dim3(8), dim3(256), 0, stream, sprotos, ws);
    hipLaunchKernelGGL(k_stageA_part, dim3(3, 32, EPI), dim3(192), 0, stream, qft, un, ws);
    hipLaunchKernelGGL(k_stageA_fin, dim3(9, 4, EPI), dim3(256), 0, stream, ws, out);
    hipLaunchKernelGGL(k_initcent, dim3(8, 5, EPI), dim3(256), 0, stream, un, ws);
    for (int it = 0; it < KM_IT; ++it) {
        hipLaunchKernelGGL(k_d0part, dim3(18, 16, EPI), dim3(192), 0, stream, un, ws);
        hipLaunchKernelGGL(k_d0red, dim3(310), dim3(256), 0, stream, ws);
        hipLaunchKernelGGL(k_assign, dim3(432, EPI), dim3(64), 0, stream, ws, afg, abg);
        hipLaunchKernelGGL(k_gatherA, dim3(27, EPI), dim3(256), 0, stream, ws, afg, abg);
        hipLaunchKernelGGL(k_numpart, dim3(8, NSTRIPS, EPI), dim3(256), 0, stream, un, ws);
        hipLaunchKernelGGL(k_centup, dim3(320), dim3(256), 0, stream, ws);
    }
    hipLaunchKernelGGL(k_buildP12, dim3(48), dim3(256), 0, stream, ws);
    hipLaunchKernelGGL(k_pred_part, dim3(3, 8, EPI), dim3(192), 0, stream, qft, ws);
    hipLaunchKernelGGL(k_pred_fin, dim3(9, EPI), dim3(256), 0, stream, ws);
    hipLaunchKernelGGL(k_resize, dim3(5435), dim3(256), 0, stream, ws, out);
}

// Round 6
// 1613.400 us; speedup vs baseline: 1.1073x; 1.0162x over previous
//
#include <hip/hip_runtime.h>
#include <math.h>

#define EPI   4
#define NCH   2048
#define HH    48
#define HW    2304          // 48*48
#define NU    3
#define STOT  6912          // NU*HW
#define UP    96
#define UPHW  9216
#define UPS   27648
#define K10   10
#define KM_IT 10
#define OUTD  417
#define OUTHW 173889
#define MASK_OFF 1391112    // 8*417*417
#define EPSF  1e-8f
#define SCL   20.0f

// workspace offsets (floats)
#define OFF_PNBG  0          // [4][2048]
#define OFF_PNFG  8192       // [4][2048]
#define OFF_PBF   16384      // [4][2048][2] interleaved (bg,fg)
#define OFF_NORMQ 32768      // [4][2304]
#define OFF_WFG   41984      // [4][3][2304]
#define OFF_WBG   69632      // [4][3][2304]
#define OFF_CENT  97280      // [4][10][2048]
#define OFF_CT12  179200     // [4][2048][12]  centroid transpose, padded
#define OFF_P12   277504     // [4][2048][12]  final protos, padded
#define OFF_C2    375808     // [4][10]
#define OFF_DENP  375848     // [4][27][10]
#define OFF_D0    376928     // [4][10][6912]
#define OFF_AT12  653408     // [4][6912][12]  padded
#define OFF_D0P   985184     // [16][4][10][6912]
#define OFF_NUMP  5408864    // [4][48][10][2048]  (48 strip partials)
#define OFF_OUTS  9341024    // [4][2][2304]
#define OFF_K1P   9359456    // [4][4][8][3][2304]
#define OFF_KHP   10244192   // [4][32][12][2304]  (32 channel chunks)
#define ASSIGN_BYTE_OFF 55132544   // 13783136 floats * 4

// numpart tiling
#define NSTRIPS   48         // 16 strips/img * 3 imgs
#define SSTRIP    144        // locs per strip (2304/16)
#define STILE     16         // locs per LDS tile
#define LDSROW    257        // 256 channels + 1 pad (odd stride -> 2-way banks)

__device__ __forceinline__ void blc(int o, double scale, int hi, int& i0, int& i1, float& w) {
    double v = (double)o * scale;
    int a = (int)v;
    i0 = a;
    i1 = (a + 1 < hi) ? a + 1 : hi;
    w = (float)(v - (double)a);
}

__device__ __forceinline__ float blockReduce256(float v, float* red) {
    int t = threadIdx.x;
    red[t] = v; __syncthreads();
    for (int s = 128; s > 0; s >>= 1) {
        if (t < s) red[t] += red[t + s];
        __syncthreads();
    }
    float r = red[0]; __syncthreads();
    return r;
}

// ---------- K0: normalize sprotos -> pn_bg / pn_fg + interleaved pbf ----------
__global__ __launch_bounds__(256) void k_protonorm(const float* __restrict__ sprotos, float* __restrict__ ws) {
    int epi = blockIdx.x >> 1, which = blockIdx.x & 1;
    const float* p = sprotos + (size_t)(epi * 2 + which) * NCH;
    __shared__ float red[256];
    float ss = 0.f;
    for (int c = threadIdx.x; c < NCH; c += 256) { float v = p[c]; ss = fmaf(v, v, ss); }
    float tot = blockReduce256(ss, red);
    float denom = fmaxf(sqrtf(tot), EPSF);
    float* outp = ws + (which ? OFF_PNFG : OFF_PNBG) + (size_t)epi * NCH;
    for (int c = threadIdx.x; c < NCH; c += 256) {
        float v = p[c] / denom;
        outp[c] = v;
        ws[OFF_PBF + ((size_t)epi * NCH + c) * 2 + which] = v;
    }
}

// ---------- K1a: stage-A partials, 1 loc/thread for occupancy (18 waves/CU) ----------
// Per-loc ss/db/df chains over 256 channels identical to verified version -> bit-exact.
__global__ __launch_bounds__(192) void k_stageA_part(const float* __restrict__ qft, const float* __restrict__ un,
                                                     float* __restrict__ ws) {
    int epi = blockIdx.z;
    int img = blockIdx.y >> 3, cc = blockIdx.y & 7;
    int loc = blockIdx.x * 192 + threadIdx.x;   // 0..2303 (grid.x = 12)
    const float* base = (img == 0) ? (qft + (size_t)epi * NCH * HW)
                                   : (un + (size_t)(epi * NU + img - 1) * NCH * HW);
    int c0 = cc * 256;
    const float* p = base + (size_t)c0 * HW + loc;
    const float2* pbf = (const float2*)(ws + OFF_PBF) + (size_t)epi * NCH + c0;
    float ss = 0.f, db = 0.f, df = 0.f;
    for (int i = 0; i < 256; ++i) {
        float x = p[(size_t)i * HW];
        float2 bf = pbf[i];
        ss = fmaf(x, x, ss);
        db = fmaf(x, bf.x, db);
        df = fmaf(x, bf.y, df);
    }
    float* k1p = ws + OFF_K1P + (((size_t)(epi * 4 + img) * 8 + cc) * 3) * HW;
    k1p[loc] = ss;
    k1p[HW + loc] = db;
    k1p[2 * HW + loc] = df;
}

// ---------- K1b: finish stage A ----------
__global__ __launch_bounds__(256) void k_stageA_fin(float* __restrict__ ws, float* __restrict__ dout) {
    int epi = blockIdx.z, img = blockIdx.y;
    int loc = blockIdx.x * 256 + threadIdx.x;
    float ss = 0.f, db = 0.f, df = 0.f;
    for (int cc = 0; cc < 8; ++cc) {
        const float* k1p = ws + OFF_K1P + (((size_t)(epi * 4 + img) * 8 + cc) * 3) * HW + loc;
        ss += k1p[0]; db += k1p[HW]; df += k1p[2 * HW];
    }
    float denom = fmaxf(sqrtf(ss), EPSF);
    float sb = SCL * (db / denom), sf = SCL * (df / denom);
    float m = fmaxf(sb, sf);
    float eb = expf(sb - m), ef = expf(sf - m);
    float s = eb + ef;
    float hb = rintf(eb / s), hf = rintf(ef / s);
    if (img == 0) {
        dout[MASK_OFF + (size_t)(epi * 2) * HW + loc] = hb;
        dout[MASK_OFF + (size_t)(epi * 2 + 1) * HW + loc] = hf;
        ws[OFF_NORMQ + (size_t)epi * HW + loc] = denom;
    } else {
        ws[OFF_WBG + (size_t)(epi * NU + img - 1) * HW + loc] = hb;
        ws[OFF_WFG + (size_t)(epi * NU + img - 1) * HW + loc] = hf;
    }
}

// ---------- K2: initial centroids ----------
__global__ __launch_bounds__(256) void k_initcent(const float* __restrict__ un, float* __restrict__ ws) {
    const int sn[5] = {0, 0, 1, 2, 2};
    const int syo[5] = {0, 71, 47, 23, 95};
    const int sxo[5] = {0, 95, 95, 95, 95};
    int epi = blockIdx.z, j = blockIdx.y;
    int c = blockIdx.x * 256 + threadIdx.x;
    int n = sn[j], yo = syo[j], xo = sxo[j];
    int y0, y1, x0, x1; float wy, wx;
    blc(yo, 47.0 / 95.0, 47, y0, y1, wy);
    blc(xo, 47.0 / 95.0, 47, x0, x1, wx);
    const float* p = un + ((size_t)(epi * NU + n) * NCH + c) * HW;
    float v00 = p[y0 * HH + x0], v10 = p[y1 * HH + x0];
    float v01 = p[y0 * HH + x1], v11 = p[y1 * HH + x1];
    float t0 = v00 * (1.f - wy) + v10 * wy;
    float t1 = v01 * (1.f - wy) + v11 * wy;
    float val = t0 * (1.f - wx) + t1 * wx;
    float* cent = ws + OFF_CENT + (size_t)epi * K10 * NCH;
    cent[(size_t)j * NCH + c] = val;
    cent[(size_t)(j + 5) * NCH + c] = val;
    float* ct = ws + OFF_CT12 + ((size_t)epi * NCH + c) * 12;
    ct[j] = val; ct[j + 5] = val;
}

#define STEP10(A, VX) \
    A[0]=fmaf(VX,ca.x,A[0]); A[1]=fmaf(VX,ca.y,A[1]); A[2]=fmaf(VX,ca.z,A[2]); A[3]=fmaf(VX,ca.w,A[3]); \
    A[4]=fmaf(VX,cb.x,A[4]); A[5]=fmaf(VX,cb.y,A[5]); A[6]=fmaf(VX,cb.z,A[6]); A[7]=fmaf(VX,cb.w,A[7]); \
    A[8]=fmaf(VX,cd.x,A[8]); A[9]=fmaf(VX,cd.y,A[9]);

// ---------- KA: D0 partials, 1 loc/thread (27 waves/CU); chains bit-exact ----------
__global__ __launch_bounds__(192) void k_d0part(const float* __restrict__ un, float* __restrict__ ws) {
    int epi = blockIdx.z, cch = blockIdx.y;      // 16 chunks x 128 c
    int c0 = cch * 128;
    int s = blockIdx.x * 192 + threadIdx.x;      // 0..6911 (grid.x = 36)
    int n = s / HW, l = s % HW;
    const float* p = un + ((size_t)(epi * NU + n) * NCH + c0) * HW + l;
    const float4* ct = (const float4*)(ws + OFF_CT12 + ((size_t)epi * NCH + c0) * 12);
    float a[K10];
#pragma unroll
    for (int j = 0; j < K10; ++j) a[j] = 0.f;
    for (int cc = 0; cc < 128; ++cc) {
        float x = p[(size_t)cc * HW];
        float4 ca = ct[cc * 3], cb = ct[cc * 3 + 1], cd = ct[cc * 3 + 2];
        STEP10(a, x)
    }
    float* d0p = ws + OFF_D0P + (size_t)cch * (EPI * K10 * STOT) + (size_t)epi * K10 * STOT;
#pragma unroll
    for (int j = 0; j < K10; ++j)
        d0p[(size_t)j * STOT + s] = a[j];
}

// ---------- KA2: reduce D0 partials (float4) + c2 ----------
__global__ __launch_bounds__(256) void k_d0red(float* __restrict__ ws) {
    __shared__ float red[256];
    int bid = blockIdx.x;
    if (bid < 270) {
        int idx4 = bid * 256 + threadIdx.x;     // float4 index < 69120
        const float4* src = (const float4*)(ws + OFF_D0P) + idx4;
        float4 a = make_float4(0.f, 0.f, 0.f, 0.f);
        for (int cc = 0; cc < 16; ++cc) {
            float4 v = src[(size_t)cc * 69120];
            a.x += v.x; a.y += v.y; a.z += v.z; a.w += v.w;
        }
        *((float4*)(ws + OFF_D0) + idx4) = a;
    } else {
        int b = bid - 270;                      // epi*10+j
        const float* cent = ws + OFF_CENT + (size_t)b * NCH;
        float ss = 0.f;
        for (int c = threadIdx.x; c < NCH; c += 256) { float v = cent[c]; ss = fmaf(v, v, ss); }
        float tot = blockReduce256(ss, red);
        if (threadIdx.x == 0) ws[OFF_C2 + b] = tot;
    }
}

// ---------- KC: assignments (64-thr blocks spread across all CUs) ----------
__global__ __launch_bounds__(64) void k_assign(const float* __restrict__ ws,
                                               unsigned char* __restrict__ afg,
                                               unsigned char* __restrict__ abg) {
    int epi = blockIdx.y;
    int i = blockIdx.x * 64 + threadIdx.x;      // 0..27647 (grid.x = 432)
    int n = i / UPHW, r = i % UPHW, yo = r / UP, xo = r % UP;
    int y0, y1, x0, x1; float wy, wx;
    blc(yo, 47.0 / 95.0, 47, y0, y1, wy);
    blc(xo, 47.0 / 95.0, 47, x0, x1, wx);
    int sb = n * HW;
    int s00 = sb + y0 * HH + x0, s10 = sb + y1 * HH + x0;
    int s01 = sb + y0 * HH + x1, s11 = sb + y1 * HH + x1;
    const float* D0 = ws + OFF_D0 + (size_t)epi * K10 * STOT;
    const float* c2 = ws + OFF_C2 + epi * K10;
    float dots[K10];
#pragma unroll
    for (int j = 0; j < K10; ++j) {
        const float* dj = D0 + (size_t)j * STOT;
        float t0 = dj[s00] * (1.f - wy) + dj[s10] * wy;
        float t1 = dj[s01] * (1.f - wy) + dj[s11] * wy;
        dots[j] = t0 * (1.f - wx) + t1 * wx;
    }
    int bf = 0; float best = fmaf(-2.f, dots[0], c2[0]);
#pragma unroll
    for (int j = 1; j < 5; ++j) { float sc = fmaf(-2.f, dots[j], c2[j]); if (sc < best) { best = sc; bf = j; } }
    int bb = 0; best = fmaf(-2.f, dots[5], c2[5]);
#pragma unroll
    for (int j = 1; j < 5; ++j) { float sc = fmaf(-2.f, dots[5 + j], c2[5 + j]); if (sc < best) { best = sc; bb = j; } }
    afg[(size_t)epi * UPS + i] = (unsigned char)bf;
    abg[(size_t)epi * UPS + i] = (unsigned char)bb;
}

// ---------- KD: gather A^T rows (padded to 12) + block-partial dens ----------
__global__ __launch_bounds__(256) void k_gatherA(float* __restrict__ ws,
                                                 const unsigned char* __restrict__ afg,
                                                 const unsigned char* __restrict__ abg) {
    __shared__ float red2[10][256];
    int epi = blockIdx.y;
    int s = blockIdx.x * 256 + threadIdx.x;     // 0..6911
    int n = s / HW, loc = s % HW, y = loc / HH, x = loc % HH;

    int yov[6]; float wyv[6]; int nyc = 0;
    int xov[6]; float wxv[6]; int nxc = 0;
#pragma unroll 1
    for (int t = 0; t < 6; ++t) { yov[t] = 0; wyv[t] = 0.f; xov[t] = 0; wxv[t] = 0.f; }
    for (int yo = 0; yo < UP; ++yo) {
        double v = (double)yo * (47.0 / 95.0);
        int a = (int)v; int b = (a + 1 < 47) ? a + 1 : 47;
        float w = (float)(v - (double)a);
        float ctr = ((a == y) ? (1.f - w) : 0.f) + ((b == y) ? w : 0.f);
        if (ctr > 0.f && nyc < 6) { yov[nyc] = yo; wyv[nyc] = ctr; ++nyc; }
    }
    for (int xo = 0; xo < UP; ++xo) {
        double v = (double)xo * (47.0 / 95.0);
        int a = (int)v; int b = (a + 1 < 47) ? a + 1 : 47;
        float w = (float)(v - (double)a);
        float ctr = ((a == x) ? (1.f - w) : 0.f) + ((b == x) ? w : 0.f);
        if (ctr > 0.f && nxc < 6) { xov[nxc] = xo; wxv[nxc] = ctr; ++nxc; }
    }
    float Af[5] = {0, 0, 0, 0, 0}, Ab[5] = {0, 0, 0, 0, 0};
    const unsigned char* fa = afg + (size_t)epi * UPS;
    const unsigned char* ba = abg + (size_t)epi * UPS;
    const float* WF = ws + OFF_WFG + (size_t)(epi * NU + n) * HW;
    const float* WB = ws + OFF_WBG + (size_t)(epi * NU + n) * HW;
#pragma unroll
    for (int a = 0; a < 6; ++a) {
#pragma unroll
        for (int b = 0; b < 6; ++b) {
            int yo = yov[a], xo = xov[b];
            int i = n * UPHW + yo * UP + xo;
            float coef = wyv[a] * wxv[b];
            int mi = (yo >> 1) * HH + (xo >> 1);
            float cf = coef * WF[mi], cb = coef * WB[mi];
            int jf = fa[i], jb = ba[i];
#pragma unroll
            for (int j = 0; j < 5; ++j) {
                Af[j] += (jf == j) ? cf : 0.f;
                Ab[j] += (jb == j) ? cb : 0.f;
            }
        }
    }
    float* at = ws + OFF_AT12 + ((size_t)epi * STOT + s) * 12;
#pragma unroll
    for (int j = 0; j < 5; ++j) { at[j] = Af[j]; at[5 + j] = Ab[j]; }
    // block-partial dens (fg j=0..4, bg j=5..9)
    int t = threadIdx.x;
#pragma unroll
    for (int j = 0; j < 5; ++j) { red2[j][t] = Af[j]; red2[5 + j][t] = Ab[j]; }
    __syncthreads();
    for (int st = 128; st > 0; st >>= 1) {
        for (int e = t; e < 10 * st; e += 256) {
            int j = e / st, i2 = e % st;
            red2[j][i2] += red2[j][i2 + st];
        }
        __syncthreads();
    }
    if (t < 10) ws[OFF_DENP + ((size_t)epi * 27 + blockIdx.x) * 10 + t] = red2[t][0];
}

// ---------- KF: num partials, LDS-tiled transpose-consume ----------
__global__ __launch_bounds__(256) void k_numpart(const float* __restrict__ un, float* __restrict__ ws) {
    __shared__ float tile[STILE * LDSROW];      // 16 x 257 floats = 16.4 KB
    int epi = blockIdx.z;
    int strip = blockIdx.y;                     // 0..47
    int c0 = blockIdx.x * 256;                  // 8 chunks
    int n = strip >> 4;
    int loc0 = (strip & 15) * SSTRIP;
    int t = threadIdx.x;
    int cl = t >> 2;                            // 0..63
    int si0 = (t & 3) * 4;                      // 0,4,8,12
    float acc[K10];
#pragma unroll
    for (int j = 0; j < K10; ++j) acc[j] = 0.f;
    const float* ubase = un + ((size_t)(epi * NU + n) * NCH + c0) * HW + loc0;
    const float* atbase = ws + OFF_AT12 + ((size_t)epi * STOT + n * HW + loc0) * 12;
    for (int tt = 0; tt < SSTRIP / STILE; ++tt) {
#pragma unroll
        for (int pass = 0; pass < 4; ++pass) {
            int c = cl + 64 * pass;
            float4 v = *(const float4*)(ubase + (size_t)c * HW + tt * STILE + si0);
            tile[(si0 + 0) * LDSROW + c] = v.x;
            tile[(si0 + 1) * LDSROW + c] = v.y;
            tile[(si0 + 2) * LDSROW + c] = v.z;
            tile[(si0 + 3) * LDSROW + c] = v.w;
        }
        __syncthreads();
#pragma unroll
        for (int si = 0; si < STILE; ++si) {
            float x = tile[si * LDSROW + t];
            const float* at = atbase + (size_t)(tt * STILE + si) * 12;
#pragma unroll
            for (int j = 0; j < K10; ++j) acc[j] = fmaf(x, at[j], acc[j]);
        }
        __syncthreads();
    }
    float* np = ws + OFF_NUMP + ((size_t)(epi * NSTRIPS + strip) * K10) * NCH + c0 + t;
#pragma unroll
    for (int j = 0; j < K10; ++j) np[(size_t)j * NCH] = acc[j];
}

// ---------- KF2: centroid update (den finish + CT12 write) ----------
__global__ __launch_bounds__(256) void k_centup(float* __restrict__ ws) {
    __shared__ float sden;
    int idx = blockIdx.x * 256 + threadIdx.x;   // < 81920
    int epi = idx / (K10 * NCH);
    int r = idx - epi * K10 * NCH;
    int j = r >> 11, c = r & 2047;
    if (threadIdx.x == 0) {
        float d = 0.f;
        for (int b = 0; b < 27; ++b) d += ws[OFF_DENP + ((size_t)epi * 27 + b) * 10 + j];
        sden = d;
    }
    __syncthreads();
    float num = 0.f;
#pragma unroll 8
    for (int sc = 0; sc < NSTRIPS; ++sc)
        num += ws[OFF_NUMP + ((size_t)(epi * NSTRIPS + sc) * K10 + j) * NCH + c];
    float d = sden;
    size_t ci = OFF_CENT + ((size_t)epi * K10 + j) * NCH + c;
    float newv = (d > 0.f) ? num / (d + EPSF) : ws[ci];
    ws[ci] = newv;
    ws[OFF_CT12 + ((size_t)epi * NCH + c) * 12 + j] = newv;
}

// ---------- KG: build normalized 12-proto interleaved matrix ----------
__global__ __launch_bounds__(256) void k_buildP12(float* __restrict__ ws) {
    __shared__ float red[256];
    int b = blockIdx.x;                        // epi*12+r
    int epi = b / 12, r = b % 12;
    const float* src;
    bool copy = false;
    if (r == 0)      { src = ws + OFF_PNBG + (size_t)epi * NCH; copy = true; }
    else if (r < 6)  { src = ws + OFF_CENT + ((size_t)epi * K10 + 4 + r) * NCH; }   // bg_cls j=5..9
    else if (r == 6) { src = ws + OFF_PNFG + (size_t)epi * NCH; copy = true; }
    else             { src = ws + OFF_CENT + ((size_t)epi * K10 + r - 7) * NCH; }   // fg_cls j=0..4
    float denom = 1.f;
    if (!copy) {
        float ss = 0.f;
        for (int c = threadIdx.x; c < NCH; c += 256) { float v = src[c]; ss = fmaf(v, v, ss); }
        float tot = blockReduce256(ss, red);
        denom = fmaxf(sqrtf(tot), EPSF);
    }
    for (int c = threadIdx.x; c < NCH; c += 256)
        ws[OFF_P12 + ((size_t)epi * NCH + c) * 12 + r] = src[c] / denom;
}

#define STEP12(A, VX) \
    A[0]=fmaf(VX,pa.x,A[0]); A[1]=fmaf(VX,pa.y,A[1]); A[2]=fmaf(VX,pa.z,A[2]); A[3]=fmaf(VX,pa.w,A[3]); \
    A[4]=fmaf(VX,pb.x,A[4]); A[5]=fmaf(VX,pb.y,A[5]); A[6]=fmaf(VX,pb.z,A[6]); A[7]=fmaf(VX,pb.w,A[7]); \
    A[8]=fmaf(VX,pc.x,A[8]); A[9]=fmaf(VX,pc.y,A[9]); A[10]=fmaf(VX,pc.z,A[10]); A[11]=fmaf(VX,pc.w,A[11]);

// ---------- KHa: final sims vs 12 protos, 64-ch chunks x 1 loc/thread (18 waves/CU) ----------
__global__ __launch_bounds__(192) void k_pred_part(const float* __restrict__ qft, float* __restrict__ ws) {
    int epi = blockIdx.z, cc = blockIdx.y;      // 0..31, 64 channels each
    int c0 = cc * 64;
    int loc = blockIdx.x * 192 + threadIdx.x;   // 0..2303 (grid.x = 12)
    const float* q = qft + ((size_t)epi * NCH + c0) * HW + loc;
    const float4* pr = (const float4*)(ws + OFF_P12 + ((size_t)epi * NCH + c0) * 12);
    float a[12];
#pragma unroll
    for (int r = 0; r < 12; ++r) a[r] = 0.f;
    for (int i = 0; i < 64; ++i) {
        float x = q[(size_t)i * HW];
        float4 pa = pr[i * 3], pb = pr[i * 3 + 1], pc = pr[i * 3 + 2];
        STEP12(a, x)
    }
    float* khp = ws + OFF_KHP + ((size_t)(epi * 32 + cc) * 12) * HW;
#pragma unroll
    for (int r = 0; r < 12; ++r)
        khp[(size_t)r * HW + loc] = a[r];
}

// ---------- KHb: reduce 32 chunks, max over protos, softmax ----------
__global__ __launch_bounds__(256) void k_pred_fin(float* __restrict__ ws) {
    int epi = blockIdx.y;
    int loc = blockIdx.x * 256 + threadIdx.x;
    float dot[12];
#pragma unroll
    for (int r = 0; r < 12; ++r) dot[r] = 0.f;
    for (int cc = 0; cc < 32; ++cc) {
        const float* khp = ws + OFF_KHP + ((size_t)(epi * 32 + cc) * 12) * HW + loc;
#pragma unroll
        for (int r = 0; r < 12; ++r) dot[r] += khp[(size_t)r * HW];
    }
    float mb = dot[0];
#pragma unroll
    for (int r = 1; r < 6; ++r) mb = fmaxf(mb, dot[r]);
    float mf = dot[6];
#pragma unroll
    for (int r = 7; r < 12; ++r) mf = fmaxf(mf, dot[r]);
    float denom = ws[OFF_NORMQ + (size_t)epi * HW + loc];
    float sb = SCL * (mb / denom), sf = SCL * (mf / denom);
    float m = fmaxf(sb, sf);
    float eb = expf(sb - m), ef = expf(sf - m);
    float ssum = eb + ef;
    ws[OFF_OUTS + (size_t)(epi * 2) * HW + loc] = eb / ssum;
    ws[OFF_OUTS + (size_t)(epi * 2 + 1) * HW + loc] = ef / ssum;
}

// ---------- KI: bilinear resize 48x48 -> 417x417 ----------
__global__ __launch_bounds__(256) void k_resize(const float* __restrict__ ws, float* __restrict__ dout) {
    int idx = blockIdx.x * 256 + threadIdx.x;
    if (idx >= 8 * OUTHW) return;
    int img = idx / OUTHW, r = idx - img * OUTHW;
    int yo = r / OUTD, xo = r - yo * OUTD;
    int y0, y1, x0, x1; float wy, wx;
    blc(yo, 47.0 / 416.0, 47, y0, y1, wy);
    blc(xo, 47.0 / 416.0, 47, x0, x1, wx);
    const float* src = ws + OFF_OUTS + (size_t)img * HW;
    float t0 = src[y0 * HH + x0] * (1.f - wy) + src[y1 * HH + x0] * wy;
    float t1 = src[y0 * HH + x1] * (1.f - wy) + src[y1 * HH + x1] * wy;
    dout[idx] = t0 * (1.f - wx) + t1 * wx;
}

extern "C" void kernel_launch(void* const* d_in, const int* in_sizes, int n_in,
                              void* d_out, int out_size, void* d_ws, size_t ws_size,
                              hipStream_t stream) {
    const float* sprotos = (const float*)d_in[0];
    const float* qft     = (const float*)d_in[1];
    const float* un      = (const float*)d_in[2];
    float* ws  = (float*)d_ws;
    float* out = (float*)d_out;
    unsigned char* afg = (unsigned char*)d_ws + ASSIGN_BYTE_OFF;
    unsigned char* abg = afg + (size_t)EPI * UPS;

    hipLaunchKernelGGL(k_protonorm, dim3(8), dim3(256), 0, stream, sprotos, ws);
    hipLaunchKernelGGL(k_stageA_part, dim3(12, 32, EPI), dim3(192), 0, stream, qft, un, ws);
    hipLaunchKernelGGL(k_stageA_fin, dim3(9, 4, EPI), dim3(256), 0, stream, ws, out);
    hipLaunchKernelGGL(k_initcent, dim3(8, 5, EPI), dim3(256), 0, stream, un, ws);
    for (int it = 0; it < KM_IT; ++it) {
        hipLaunchKernelGGL(k_d0part, dim3(36, 16, EPI), dim3(192), 0, stream, un, ws);
        hipLaunchKernelGGL(k_d0red, dim3(310), dim3(256), 0, stream, ws);
        hipLaunchKernelGGL(k_assign, dim3(432, EPI), dim3(64), 0, stream, ws, afg, abg);
        hipLaunchKernelGGL(k_gatherA, dim3(27, EPI), dim3(256), 0, stream, ws, afg, abg);
        hipLaunchKernelGGL(k_numpart, dim3(8, NSTRIPS, EPI), dim3(256), 0, stream, un, ws);
        hipLaunchKernelGGL(k_centup, dim3(320), dim3(256), 0, stream, ws);
    }
    hipLaunchKernelGGL(k_buildP12, dim3(48), dim3(256), 0, stream, ws);
    hipLaunchKernelGGL(k_pred_part, dim3(12, 32, EPI), dim3(192), 0, stream, qft, ws);
    hipLaunchKernelGGL(k_pred_fin, dim3(9, EPI), dim3(256), 0, stream, ws);
    hipLaunchKernelGGL(k_resize, dim3(5435), dim3(256), 0, stream, ws, out);
}

// Round 7
// 1438.820 us; speedup vs baseline: 1.2417x; 1.1213x over previous
//
#include <hip/hip_runtime.h>
#include <math.h>

#define EPI   4
#define NCH   2048
#define HH    48
#define HW    2304          // 48*48
#define NU    3
#define STOT  6912          // NU*HW
#define UP    96
#define UPHW  9216
#define UPS   27648
#define K10   10
#define KM_IT 10
#define OUTD  417
#define OUTHW 173889
#define MASK_OFF 1391112    // 8*417*417
#define EPSF  1e-8f
#define SCL   20.0f

// workspace offsets (floats)
#define OFF_PNBG  0          // [4][2048]
#define OFF_PNFG  8192       // [4][2048]
#define OFF_PBF   16384      // [4][2048][2] interleaved (bg,fg)
#define OFF_NORMQ 32768      // [4][2304]
#define OFF_WFG   41984      // [4][3][2304]
#define OFF_WBG   69632      // [4][3][2304]
#define OFF_CENT  97280      // [4][10][2048]
#define OFF_CT12  179200     // [4][2048][12]  centroid transpose, padded
#define OFF_P12   277504     // [4][2048][12]  final protos, padded
#define OFF_C2    375808     // [4][10]
#define OFF_DENP  375848     // [4][27][10]
#define OFF_D0    376928     // [4][10][6912]
#define OFF_AT12  653408     // [4][6912][12]  padded
#define OFF_D0P   985184     // [16][4][10][6912]
#define OFF_NUMP  5408864    // [4][48][10][2048]  (48 strip partials)
#define OFF_OUTS  9341024    // [4][2][2304]
#define OFF_K1P   9359456    // [4][4][8][3][2304]
#define OFF_KHP   10244192   // [4][32][12][2304]  (32 channel chunks)
#define OFF_BTAB  13783136   // [48][6] float2 bilinear contribution table (576 floats)
#define ASSIGN_BYTE_OFF 55134848   // 13783712 floats * 4

// numpart tiling
#define NSTRIPS   48         // 16 strips/img * 3 imgs
#define SSTRIP    144        // locs per strip (2304/16)
#define STILE     16         // locs per LDS tile
#define LDSROW    257        // 256 channels + 1 pad (odd stride -> 2-way banks)

__device__ __forceinline__ void blc(int o, double scale, int hi, int& i0, int& i1, float& w) {
    double v = (double)o * scale;
    int a = (int)v;
    i0 = a;
    i1 = (a + 1 < hi) ? a + 1 : hi;
    w = (float)(v - (double)a);
}

__device__ __forceinline__ float blockReduce256(float v, float* red) {
    int t = threadIdx.x;
    red[t] = v; __syncthreads();
    for (int s = 128; s > 0; s >>= 1) {
        if (t < s) red[t] += red[t + s];
        __syncthreads();
    }
    float r = red[0]; __syncthreads();
    return r;
}

// ---------- K0: normalize sprotos -> pn_bg / pn_fg + interleaved pbf ----------
__global__ __launch_bounds__(256) void k_protonorm(const float* __restrict__ sprotos, float* __restrict__ ws) {
    int epi = blockIdx.x >> 1, which = blockIdx.x & 1;
    const float* p = sprotos + (size_t)(epi * 2 + which) * NCH;
    __shared__ float red[256];
    float ss = 0.f;
    for (int c = threadIdx.x; c < NCH; c += 256) { float v = p[c]; ss = fmaf(v, v, ss); }
    float tot = blockReduce256(ss, red);
    float denom = fmaxf(sqrtf(tot), EPSF);
    float* outp = ws + (which ? OFF_PNFG : OFF_PNBG) + (size_t)epi * NCH;
    for (int c = threadIdx.x; c < NCH; c += 256) {
        float v = p[c] / denom;
        outp[c] = v;
        ws[OFF_PBF + ((size_t)epi * NCH + c) * 2 + which] = v;
    }
}

// ---------- Kbtab: bilinear contribution table, one thread per y in [0,48) ----------
// Same ascending-yo scan + float arithmetic as the original in-kernel search -> bit-exact.
__global__ __launch_bounds__(64) void k_btab(float* __restrict__ ws) {
    int y = threadIdx.x;
    if (y >= 48) return;
    float2* tab = (float2*)(ws + OFF_BTAB) + y * 6;
    int n = 0;
#pragma unroll 1
    for (int yo = 0; yo < UP; ++yo) {
        double v = (double)yo * (47.0 / 95.0);
        int a = (int)v; int b = (a + 1 < 47) ? a + 1 : 47;
        float w = (float)(v - (double)a);
        float ctr = ((a == y) ? (1.f - w) : 0.f) + ((b == y) ? w : 0.f);
        if (ctr > 0.f && n < 6) { tab[n] = make_float2((float)yo, ctr); ++n; }
    }
    for (; n < 6; ++n) tab[n] = make_float2(0.f, 0.f);
}

// ---------- K1a: stage-A partials, 1 loc/thread ----------
__global__ __launch_bounds__(192) void k_stageA_part(const float* __restrict__ qft, const float* __restrict__ un,
                                                     float* __restrict__ ws) {
    int epi = blockIdx.z;
    int img = blockIdx.y >> 3, cc = blockIdx.y & 7;
    int loc = blockIdx.x * 192 + threadIdx.x;   // 0..2303 (grid.x = 12)
    const float* base = (img == 0) ? (qft + (size_t)epi * NCH * HW)
                                   : (un + (size_t)(epi * NU + img - 1) * NCH * HW);
    int c0 = cc * 256;
    const float* p = base + (size_t)c0 * HW + loc;
    const float2* pbf = (const float2*)(ws + OFF_PBF) + (size_t)epi * NCH + c0;
    float ss = 0.f, db = 0.f, df = 0.f;
    for (int i = 0; i < 256; ++i) {
        float x = p[(size_t)i * HW];
        float2 bf = pbf[i];
        ss = fmaf(x, x, ss);
        db = fmaf(x, bf.x, db);
        df = fmaf(x, bf.y, df);
    }
    float* k1p = ws + OFF_K1P + (((size_t)(epi * 4 + img) * 8 + cc) * 3) * HW;
    k1p[loc] = ss;
    k1p[HW + loc] = db;
    k1p[2 * HW + loc] = df;
}

// ---------- K1b: finish stage A ----------
__global__ __launch_bounds__(256) void k_stageA_fin(float* __restrict__ ws, float* __restrict__ dout) {
    int epi = blockIdx.z, img = blockIdx.y;
    int loc = blockIdx.x * 256 + threadIdx.x;
    float ss = 0.f, db = 0.f, df = 0.f;
    for (int cc = 0; cc < 8; ++cc) {
        const float* k1p = ws + OFF_K1P + (((size_t)(epi * 4 + img) * 8 + cc) * 3) * HW + loc;
        ss += k1p[0]; db += k1p[HW]; df += k1p[2 * HW];
    }
    float denom = fmaxf(sqrtf(ss), EPSF);
    float sb = SCL * (db / denom), sf = SCL * (df / denom);
    float m = fmaxf(sb, sf);
    float eb = expf(sb - m), ef = expf(sf - m);
    float s = eb + ef;
    float hb = rintf(eb / s), hf = rintf(ef / s);
    if (img == 0) {
        dout[MASK_OFF + (size_t)(epi * 2) * HW + loc] = hb;
        dout[MASK_OFF + (size_t)(epi * 2 + 1) * HW + loc] = hf;
        ws[OFF_NORMQ + (size_t)epi * HW + loc] = denom;
    } else {
        ws[OFF_WBG + (size_t)(epi * NU + img - 1) * HW + loc] = hb;
        ws[OFF_WFG + (size_t)(epi * NU + img - 1) * HW + loc] = hf;
    }
}

// ---------- K2: initial centroids ----------
__global__ __launch_bounds__(256) void k_initcent(const float* __restrict__ un, float* __restrict__ ws) {
    const int sn[5] = {0, 0, 1, 2, 2};
    const int syo[5] = {0, 71, 47, 23, 95};
    const int sxo[5] = {0, 95, 95, 95, 95};
    int epi = blockIdx.z, j = blockIdx.y;
    int c = blockIdx.x * 256 + threadIdx.x;
    int n = sn[j], yo = syo[j], xo = sxo[j];
    int y0, y1, x0, x1; float wy, wx;
    blc(yo, 47.0 / 95.0, 47, y0, y1, wy);
    blc(xo, 47.0 / 95.0, 47, x0, x1, wx);
    const float* p = un + ((size_t)(epi * NU + n) * NCH + c) * HW;
    float v00 = p[y0 * HH + x0], v10 = p[y1 * HH + x0];
    float v01 = p[y0 * HH + x1], v11 = p[y1 * HH + x1];
    float t0 = v00 * (1.f - wy) + v10 * wy;
    float t1 = v01 * (1.f - wy) + v11 * wy;
    float val = t0 * (1.f - wx) + t1 * wx;
    float* cent = ws + OFF_CENT + (size_t)epi * K10 * NCH;
    cent[(size_t)j * NCH + c] = val;
    cent[(size_t)(j + 5) * NCH + c] = val;
    float* ct = ws + OFF_CT12 + ((size_t)epi * NCH + c) * 12;
    ct[j] = val; ct[j + 5] = val;
}

#define STEP10(A, VX) \
    A[0]=fmaf(VX,ca.x,A[0]); A[1]=fmaf(VX,ca.y,A[1]); A[2]=fmaf(VX,ca.z,A[2]); A[3]=fmaf(VX,ca.w,A[3]); \
    A[4]=fmaf(VX,cb.x,A[4]); A[5]=fmaf(VX,cb.y,A[5]); A[6]=fmaf(VX,cb.z,A[6]); A[7]=fmaf(VX,cb.w,A[7]); \
    A[8]=fmaf(VX,cd.x,A[8]); A[9]=fmaf(VX,cd.y,A[9]);

// ---------- KA: D0 partials, 1 loc/thread; chains bit-exact ----------
__global__ __launch_bounds__(192) void k_d0part(const float* __restrict__ un, float* __restrict__ ws) {
    int epi = blockIdx.z, cch = blockIdx.y;      // 16 chunks x 128 c
    int c0 = cch * 128;
    int s = blockIdx.x * 192 + threadIdx.x;      // 0..6911 (grid.x = 36)
    int n = s / HW, l = s % HW;
    const float* p = un + ((size_t)(epi * NU + n) * NCH + c0) * HW + l;
    const float4* ct = (const float4*)(ws + OFF_CT12 + ((size_t)epi * NCH + c0) * 12);
    float a[K10];
#pragma unroll
    for (int j = 0; j < K10; ++j) a[j] = 0.f;
    for (int cc = 0; cc < 128; ++cc) {
        float x = p[(size_t)cc * HW];
        float4 ca = ct[cc * 3], cb = ct[cc * 3 + 1], cd = ct[cc * 3 + 2];
        STEP10(a, x)
    }
    float* d0p = ws + OFF_D0P + (size_t)cch * (EPI * K10 * STOT) + (size_t)epi * K10 * STOT;
#pragma unroll
    for (int j = 0; j < K10; ++j)
        d0p[(size_t)j * STOT + s] = a[j];
}

// ---------- KA2: reduce D0 partials (float4) + c2 ----------
__global__ __launch_bounds__(256) void k_d0red(float* __restrict__ ws) {
    __shared__ float red[256];
    int bid = blockIdx.x;
    if (bid < 270) {
        int idx4 = bid * 256 + threadIdx.x;     // float4 index < 69120
        const float4* src = (const float4*)(ws + OFF_D0P) + idx4;
        float4 a = make_float4(0.f, 0.f, 0.f, 0.f);
        for (int cc = 0; cc < 16; ++cc) {
            float4 v = src[(size_t)cc * 69120];
            a.x += v.x; a.y += v.y; a.z += v.z; a.w += v.w;
        }
        *((float4*)(ws + OFF_D0) + idx4) = a;
    } else {
        int b = bid - 270;                      // epi*10+j
        const float* cent = ws + OFF_CENT + (size_t)b * NCH;
        float ss = 0.f;
        for (int c = threadIdx.x; c < NCH; c += 256) { float v = cent[c]; ss = fmaf(v, v, ss); }
        float tot = blockReduce256(ss, red);
        if (threadIdx.x == 0) ws[OFF_C2 + b] = tot;
    }
}

// ---------- KC: assignments (64-thr blocks spread across all CUs) ----------
__global__ __launch_bounds__(64) void k_assign(const float* __restrict__ ws,
                                               unsigned char* __restrict__ afg,
                                               unsigned char* __restrict__ abg) {
    int epi = blockIdx.y;
    int i = blockIdx.x * 64 + threadIdx.x;      // 0..27647 (grid.x = 432)
    int n = i / UPHW, r = i % UPHW, yo = r / UP, xo = r % UP;
    int y0, y1, x0, x1; float wy, wx;
    blc(yo, 47.0 / 95.0, 47, y0, y1, wy);
    blc(xo, 47.0 / 95.0, 47, x0, x1, wx);
    int sb = n * HW;
    int s00 = sb + y0 * HH + x0, s10 = sb + y1 * HH + x0;
    int s01 = sb + y0 * HH + x1, s11 = sb + y1 * HH + x1;
    const float* D0 = ws + OFF_D0 + (size_t)epi * K10 * STOT;
    const float* c2 = ws + OFF_C2 + epi * K10;
    float dots[K10];
#pragma unroll
    for (int j = 0; j < K10; ++j) {
        const float* dj = D0 + (size_t)j * STOT;
        float t0 = dj[s00] * (1.f - wy) + dj[s10] * wy;
        float t1 = dj[s01] * (1.f - wy) + dj[s11] * wy;
        dots[j] = t0 * (1.f - wx) + t1 * wx;
    }
    int bf = 0; float best = fmaf(-2.f, dots[0], c2[0]);
#pragma unroll
    for (int j = 1; j < 5; ++j) { float sc = fmaf(-2.f, dots[j], c2[j]); if (sc < best) { best = sc; bf = j; } }
    int bb = 0; best = fmaf(-2.f, dots[5], c2[5]);
#pragma unroll
    for (int j = 1; j < 5; ++j) { float sc = fmaf(-2.f, dots[5 + j], c2[5 + j]); if (sc < best) { best = sc; bb = j; } }
    afg[(size_t)epi * UPS + i] = (unsigned char)bf;
    abg[(size_t)epi * UPS + i] = (unsigned char)bb;
}

// ---------- KD: gather A^T rows via precomputed table (register-resident, bit-exact) ----------
__global__ __launch_bounds__(256) void k_gatherA(float* __restrict__ ws,
                                                 const unsigned char* __restrict__ afg,
                                                 const unsigned char* __restrict__ abg) {
    __shared__ float red2[10][256];
    int epi = blockIdx.y;
    int s = blockIdx.x * 256 + threadIdx.x;     // 0..6911
    int n = s / HW, loc = s % HW, y = loc / HH, x = loc % HH;

    const float2* tab = (const float2*)(ws + OFF_BTAB);
    float2 ty[6], tx[6];
#pragma unroll
    for (int t = 0; t < 6; ++t) { ty[t] = tab[y * 6 + t]; tx[t] = tab[x * 6 + t]; }

    float Af[5] = {0, 0, 0, 0, 0}, Ab[5] = {0, 0, 0, 0, 0};
    const unsigned char* fa = afg + (size_t)epi * UPS;
    const unsigned char* ba = abg + (size_t)epi * UPS;
    const float* WF = ws + OFF_WFG + (size_t)(epi * NU + n) * HW;
    const float* WB = ws + OFF_WBG + (size_t)(epi * NU + n) * HW;
#pragma unroll
    for (int a = 0; a < 6; ++a) {
#pragma unroll
        for (int b = 0; b < 6; ++b) {
            int yo = (int)ty[a].x, xo = (int)tx[b].x;
            int i = n * UPHW + yo * UP + xo;
            float coef = ty[a].y * tx[b].y;
            int mi = (yo >> 1) * HH + (xo >> 1);
            float cf = coef * WF[mi], cb = coef * WB[mi];
            int jf = fa[i], jb = ba[i];
#pragma unroll
            for (int j = 0; j < 5; ++j) {
                Af[j] += (jf == j) ? cf : 0.f;
                Ab[j] += (jb == j) ? cb : 0.f;
            }
        }
    }
    float* at = ws + OFF_AT12 + ((size_t)epi * STOT + s) * 12;
#pragma unroll
    for (int j = 0; j < 5; ++j) { at[j] = Af[j]; at[5 + j] = Ab[j]; }
    // block-partial dens (fg j=0..4, bg j=5..9)
    int t = threadIdx.x;
#pragma unroll
    for (int j = 0; j < 5; ++j) { red2[j][t] = Af[j]; red2[5 + j][t] = Ab[j]; }
    __syncthreads();
    for (int st = 128; st > 0; st >>= 1) {
        for (int e = t; e < 10 * st; e += 256) {
            int j = e / st, i2 = e % st;
            red2[j][i2] += red2[j][i2 + st];
        }
        __syncthreads();
    }
    if (t < 10) ws[OFF_DENP + ((size_t)epi * 27 + blockIdx.x) * 10 + t] = red2[t][0];
}

// ---------- KF: num partials, LDS-tiled transpose-consume ----------
__global__ __launch_bounds__(256) void k_numpart(const float* __restrict__ un, float* __restrict__ ws) {
    __shared__ float tile[STILE * LDSROW];      // 16 x 257 floats = 16.4 KB
    int epi = blockIdx.z;
    int strip = blockIdx.y;                     // 0..47
    int c0 = blockIdx.x * 256;                  // 8 chunks
    int n = strip >> 4;
    int loc0 = (strip & 15) * SSTRIP;
    int t = threadIdx.x;
    int cl = t >> 2;                            // 0..63
    int si0 = (t & 3) * 4;                      // 0,4,8,12
    float acc[K10];
#pragma unroll
    for (int j = 0; j < K10; ++j) acc[j] = 0.f;
    const float* ubase = un + ((size_t)(epi * NU + n) * NCH + c0) * HW + loc0;
    const float* atbase = ws + OFF_AT12 + ((size_t)epi * STOT + n * HW + loc0) * 12;
    for (int tt = 0; tt < SSTRIP / STILE; ++tt) {
#pragma unroll
        for (int pass = 0; pass < 4; ++pass) {
            int c = cl + 64 * pass;
            float4 v = *(const float4*)(ubase + (size_t)c * HW + tt * STILE + si0);
            tile[(si0 + 0) * LDSROW + c] = v.x;
            tile[(si0 + 1) * LDSROW + c] = v.y;
            tile[(si0 + 2) * LDSROW + c] = v.z;
            tile[(si0 + 3) * LDSROW + c] = v.w;
        }
        __syncthreads();
#pragma unroll
        for (int si = 0; si < STILE; ++si) {
            float x = tile[si * LDSROW + t];
            const float* at = atbase + (size_t)(tt * STILE + si) * 12;
#pragma unroll
            for (int j = 0; j < K10; ++j) acc[j] = fmaf(x, at[j], acc[j]);
        }
        __syncthreads();
    }
    float* np = ws + OFF_NUMP + ((size_t)(epi * NSTRIPS + strip) * K10) * NCH + c0 + t;
#pragma unroll
    for (int j = 0; j < K10; ++j) np[(size_t)j * NCH] = acc[j];
}

// ---------- KF2: centroid update (den finish + CT12 write) ----------
__global__ __launch_bounds__(256) void k_centup(float* __restrict__ ws) {
    __shared__ float sden;
    int idx = blockIdx.x * 256 + threadIdx.x;   // < 81920
    int epi = idx / (K10 * NCH);
    int r = idx - epi * K10 * NCH;
    int j = r >> 11, c = r & 2047;
    if (threadIdx.x == 0) {
        float d = 0.f;
        for (int b = 0; b < 27; ++b) d += ws[OFF_DENP + ((size_t)epi * 27 + b) * 10 + j];
        sden = d;
    }
    __syncthreads();
    float num = 0.f;
#pragma unroll 8
    for (int sc = 0; sc < NSTRIPS; ++sc)
        num += ws[OFF_NUMP + ((size_t)(epi * NSTRIPS + sc) * K10 + j) * NCH + c];
    float d = sden;
    size_t ci = OFF_CENT + ((size_t)epi * K10 + j) * NCH + c;
    float newv = (d > 0.f) ? num / (d + EPSF) : ws[ci];
    ws[ci] = newv;
    ws[OFF_CT12 + ((size_t)epi * NCH + c) * 12 + j] = newv;
}

// ---------- KG: build normalized 12-proto interleaved matrix ----------
__global__ __launch_bounds__(256) void k_buildP12(float* __restrict__ ws) {
    __shared__ float red[256];
    int b = blockIdx.x;                        // epi*12+r
    int epi = b / 12, r = b % 12;
    const float* src;
    bool copy = false;
    if (r == 0)      { src = ws + OFF_PNBG + (size_t)epi * NCH; copy = true; }
    else if (r < 6)  { src = ws + OFF_CENT + ((size_t)epi * K10 + 4 + r) * NCH; }   // bg_cls j=5..9
    else if (r == 6) { src = ws + OFF_PNFG + (size_t)epi * NCH; copy = true; }
    else             { src = ws + OFF_CENT + ((size_t)epi * K10 + r - 7) * NCH; }   // fg_cls j=0..4
    float denom = 1.f;
    if (!copy) {
        float ss = 0.f;
        for (int c = threadIdx.x; c < NCH; c += 256) { float v = src[c]; ss = fmaf(v, v, ss); }
        float tot = blockReduce256(ss, red);
        denom = fmaxf(sqrtf(tot), EPSF);
    }
    for (int c = threadIdx.x; c < NCH; c += 256)
        ws[OFF_P12 + ((size_t)epi * NCH + c) * 12 + r] = src[c] / denom;
}

#define STEP12(A, VX) \
    A[0]=fmaf(VX,pa.x,A[0]); A[1]=fmaf(VX,pa.y,A[1]); A[2]=fmaf(VX,pa.z,A[2]); A[3]=fmaf(VX,pa.w,A[3]); \
    A[4]=fmaf(VX,pb.x,A[4]); A[5]=fmaf(VX,pb.y,A[5]); A[6]=fmaf(VX,pb.z,A[6]); A[7]=fmaf(VX,pb.w,A[7]); \
    A[8]=fmaf(VX,pc.x,A[8]); A[9]=fmaf(VX,pc.y,A[9]); A[10]=fmaf(VX,pc.z,A[10]); A[11]=fmaf(VX,pc.w,A[11]);

// ---------- KHa: final sims vs 12 protos, 64-ch chunks x 1 loc/thread ----------
__global__ __launch_bounds__(192) void k_pred_part(const float* __restrict__ qft, float* __restrict__ ws) {
    int epi = blockIdx.z, cc = blockIdx.y;      // 0..31, 64 channels each
    int c0 = cc * 64;
    int loc = blockIdx.x * 192 + threadIdx.x;   // 0..2303 (grid.x = 12)
    const float* q = qft + ((size_t)epi * NCH + c0) * HW + loc;
    const float4* pr = (const float4*)(ws + OFF_P12 + ((size_t)epi * NCH + c0) * 12);
    float a[12];
#pragma unroll
    for (int r = 0; r < 12; ++r) a[r] = 0.f;
    for (int i = 0; i < 64; ++i) {
        float x = q[(size_t)i * HW];
        float4 pa = pr[i * 3], pb = pr[i * 3 + 1], pc = pr[i * 3 + 2];
        STEP12(a, x)
    }
    float* khp = ws + OFF_KHP + ((size_t)(epi * 32 + cc) * 12) * HW;
#pragma unroll
    for (int r = 0; r < 12; ++r)
        khp[(size_t)r * HW + loc] = a[r];
}

// ---------- KHb: reduce 32 chunks, max over protos, softmax ----------
__global__ __launch_bounds__(256) void k_pred_fin(float* __restrict__ ws) {
    int epi = blockIdx.y;
    int loc = blockIdx.x * 256 + threadIdx.x;
    float dot[12];
#pragma unroll
    for (int r = 0; r < 12; ++r) dot[r] = 0.f;
    for (int cc = 0; cc < 32; ++cc) {
        const float* khp = ws + OFF_KHP + ((size_t)(epi * 32 + cc) * 12) * HW + loc;
#pragma unroll
        for (int r = 0; r < 12; ++r) dot[r] += khp[(size_t)r * HW];
    }
    float mb = dot[0];
#pragma unroll
    for (int r = 1; r < 6; ++r) mb = fmaxf(mb, dot[r]);
    float mf = dot[6];
#pragma unroll
    for (int r = 7; r < 12; ++r) mf = fmaxf(mf, dot[r]);
    float denom = ws[OFF_NORMQ + (size_t)epi * HW + loc];
    float sb = SCL * (mb / denom), sf = SCL * (mf / denom);
    float m = fmaxf(sb, sf);
    float eb = expf(sb - m), ef = expf(sf - m);
    float ssum = eb + ef;
    ws[OFF_OUTS + (size_t)(epi * 2) * HW + loc] = eb / ssum;
    ws[OFF_OUTS + (size_t)(epi * 2 + 1) * HW + loc] = ef / ssum;
}

// ---------- KI: bilinear resize 48x48 -> 417x417 ----------
__global__ __launch_bounds__(256) void k_resize(const float* __restrict__ ws, float* __restrict__ dout) {
    int idx = blockIdx.x * 256 + threadIdx.x;
    if (idx >= 8 * OUTHW) return;
    int img = idx / OUTHW, r = idx - img * OUTHW;
    int yo = r / OUTD, xo = r - yo * OUTD;
    int y0, y1, x0, x1; float wy, wx;
    blc(yo, 47.0 / 416.0, 47, y0, y1, wy);
    blc(xo, 47.0 / 416.0, 47, x0, x1, wx);
    const float* src = ws + OFF_OUTS + (size_t)img * HW;
    float t0 = src[y0 * HH + x0] * (1.f - wy) + src[y1 * HH + x0] * wy;
    float t1 = src[y0 * HH + x1] * (1.f - wy) + src[y1 * HH + x1] * wy;
    dout[idx] = t0 * (1.f - wx) + t1 * wx;
}

extern "C" void kernel_launch(void* const* d_in, const int* in_sizes, int n_in,
                              void* d_out, int out_size, void* d_ws, size_t ws_size,
                              hipStream_t stream) {
    const float* sprotos = (const float*)d_in[0];
    const float* qft     = (const float*)d_in[1];
    const float* un      = (const float*)d_in[2];
    float* ws  = (float*)d_ws;
    float* out = (float*)d_out;
    unsigned char* afg = (unsigned char*)d_ws + ASSIGN_BYTE_OFF;
    unsigned char* abg = afg + (size_t)EPI * UPS;

    hipLaunchKernelGGL(k_protonorm, dim3(8), dim3(256), 0, stream, sprotos, ws);
    hipLaunchKernelGGL(k_btab, dim3(1), dim3(64), 0, stream, ws);
    hipLaunchKernelGGL(k_stageA_part, dim3(12, 32, EPI), dim3(192), 0, stream, qft, un, ws);
    hipLaunchKernelGGL(k_stageA_fin, dim3(9, 4, EPI), dim3(256), 0, stream, ws, out);
    hipLaunchKernelGGL(k_initcent, dim3(8, 5, EPI), dim3(256), 0, stream, un, ws);
    for (int it = 0; it < KM_IT; ++it) {
        hipLaunchKernelGGL(k_d0part, dim3(36, 16, EPI), dim3(192), 0, stream, un, ws);
        hipLaunchKernelGGL(k_d0red, dim3(310), dim3(256), 0, stream, ws);
        hipLaunchKernelGGL(k_assign, dim3(432, EPI), dim3(64), 0, stream, ws, afg, abg);
        hipLaunchKernelGGL(k_gatherA, dim3(27, EPI), dim3(256), 0, stream, ws, afg, abg);
        hipLaunchKernelGGL(k_numpart, dim3(8, NSTRIPS, EPI), dim3(256), 0, stream, un, ws);
        hipLaunchKernelGGL(k_centup, dim3(320), dim3(256), 0, stream, ws);
    }
    hipLaunchKernelGGL(k_buildP12, dim3(48), dim3(256), 0, stream, ws);
    hipLaunchKernelGGL(k_pred_part, dim3(12, 32, EPI), dim3(192), 0, stream, qft, ws);
    hipLaunchKernelGGL(k_pred_fin, dim3(9, EPI), dim3(256), 0, stream, ws);
    hipLaunchKernelGGL(k_resize, dim3(5435), dim3(256), 0, stream, ws, out);
}

// Round 8
// 1404.098 us; speedup vs baseline: 1.2724x; 1.0247x over previous
//
#include <hip/hip_runtime.h>
#include <math.h>

#define EPI   4
#define NCH   2048
#define HH    48
#define HW    2304          // 48*48
#define NU    3
#define STOT  6912          // NU*HW
#define UP    96
#define UPHW  9216
#define UPS   27648
#define K10   10
#define KM_IT 10
#define OUTD  417
#define OUTHW 173889
#define MASK_OFF 1391112    // 8*417*417
#define EPSF  1e-8f
#define SCL   20.0f

// workspace offsets (floats)
#define OFF_PNBG  0          // [4][2048]
#define OFF_PNFG  8192       // [4][2048]
#define OFF_PBF   16384      // [4][2048][2] interleaved (bg,fg)
#define OFF_NORMQ 32768      // [4][2304]
#define OFF_WFG   41984      // [4][3][2304]
#define OFF_WBG   69632      // [4][3][2304]
#define OFF_CENT  97280      // [4][10][2048]
#define OFF_CT12  179200     // [4][2048][12]  centroid transpose, padded
#define OFF_P12   277504     // [4][2048][12]  final protos, padded
#define OFF_C2    375808     // [4][10]
#define OFF_DENP  375848     // [4][27][10]
#define OFF_D0    376928     // [4][10][6912]
#define OFF_AT12  653408     // [4][6912][12]  padded
#define OFF_D0P   985184     // [16][4][10][6912]
#define OFF_NUMP  5408864    // [4][48][10][2048]  (48 strip partials)
#define OFF_OUTS  9341024    // [4][2][2304]
#define OFF_K1P   9359456    // [4][4][8][3][2304]
#define OFF_KHP   10244192   // [4][32][12][2304]  (32 channel chunks)
#define OFF_BTAB  13783136   // [48][6] float2 bilinear contribution table (576 floats)
#define ASSIGN_BYTE_OFF 55134848   // 13783712 floats * 4

// numpart tiling
#define NSTRIPS   48         // 16 strips/img * 3 imgs
#define SSTRIP    144        // locs per strip (2304/16)
#define STILE     16         // locs per LDS tile
#define LDSROW    257        // 256 channels + 1 pad (odd stride -> 2-way banks)

__device__ __forceinline__ void blc(int o, double scale, int hi, int& i0, int& i1, float& w) {
    double v = (double)o * scale;
    int a = (int)v;
    i0 = a;
    i1 = (a + 1 < hi) ? a + 1 : hi;
    w = (float)(v - (double)a);
}

__device__ __forceinline__ float blockReduce256(float v, float* red) {
    int t = threadIdx.x;
    red[t] = v; __syncthreads();
    for (int s = 128; s > 0; s >>= 1) {
        if (t < s) red[t] += red[t + s];
        __syncthreads();
    }
    float r = red[0]; __syncthreads();
    return r;
}

// ---------- K0: normalize sprotos -> pn_bg / pn_fg + interleaved pbf ----------
__global__ __launch_bounds__(256) void k_protonorm(const float* __restrict__ sprotos, float* __restrict__ ws) {
    int epi = blockIdx.x >> 1, which = blockIdx.x & 1;
    const float* p = sprotos + (size_t)(epi * 2 + which) * NCH;
    __shared__ float red[256];
    float ss = 0.f;
    for (int c = threadIdx.x; c < NCH; c += 256) { float v = p[c]; ss = fmaf(v, v, ss); }
    float tot = blockReduce256(ss, red);
    float denom = fmaxf(sqrtf(tot), EPSF);
    float* outp = ws + (which ? OFF_PNFG : OFF_PNBG) + (size_t)epi * NCH;
    for (int c = threadIdx.x; c < NCH; c += 256) {
        float v = p[c] / denom;
        outp[c] = v;
        ws[OFF_PBF + ((size_t)epi * NCH + c) * 2 + which] = v;
    }
}

// ---------- Kbtab: bilinear contribution table, one thread per y in [0,48) ----------
__global__ __launch_bounds__(64) void k_btab(float* __restrict__ ws) {
    int y = threadIdx.x;
    if (y >= 48) return;
    float2* tab = (float2*)(ws + OFF_BTAB) + y * 6;
    int n = 0;
#pragma unroll 1
    for (int yo = 0; yo < UP; ++yo) {
        double v = (double)yo * (47.0 / 95.0);
        int a = (int)v; int b = (a + 1 < 47) ? a + 1 : 47;
        float w = (float)(v - (double)a);
        float ctr = ((a == y) ? (1.f - w) : 0.f) + ((b == y) ? w : 0.f);
        if (ctr > 0.f && n < 6) { tab[n] = make_float2((float)yo, ctr); ++n; }
    }
    for (; n < 6; ++n) tab[n] = make_float2(0.f, 0.f);
}

// ---------- K1a: stage-A partials, float2 (8B/lane), 2 locs/thread ----------
// Per-loc ss/db/df chains over 256 channels identical -> bit-exact.
__global__ __launch_bounds__(192) void k_stageA_part(const float* __restrict__ qft, const float* __restrict__ un,
                                                     float* __restrict__ ws) {
    int epi = blockIdx.z;
    int img = blockIdx.y >> 3, cc = blockIdx.y & 7;
    int loc = (blockIdx.x * 192 + threadIdx.x) * 2;   // 0..2302 (grid.x = 6)
    const float* base = (img == 0) ? (qft + (size_t)epi * NCH * HW)
                                   : (un + (size_t)(epi * NU + img - 1) * NCH * HW);
    int c0 = cc * 256;
    const float* p = base + (size_t)c0 * HW + loc;
    const float2* pbf = (const float2*)(ws + OFF_PBF) + (size_t)epi * NCH + c0;
    float ss0 = 0.f, db0 = 0.f, df0 = 0.f;
    float ss1 = 0.f, db1 = 0.f, df1 = 0.f;
    for (int i = 0; i < 256; ++i) {
        float2 v = *(const float2*)(p + (size_t)i * HW);
        float2 bf = pbf[i];
        ss0 = fmaf(v.x, v.x, ss0); db0 = fmaf(v.x, bf.x, db0); df0 = fmaf(v.x, bf.y, df0);
        ss1 = fmaf(v.y, v.y, ss1); db1 = fmaf(v.y, bf.x, db1); df1 = fmaf(v.y, bf.y, df1);
    }
    float* k1p = ws + OFF_K1P + (((size_t)(epi * 4 + img) * 8 + cc) * 3) * HW;
    *(float2*)(k1p + loc)          = make_float2(ss0, ss1);
    *(float2*)(k1p + HW + loc)     = make_float2(db0, db1);
    *(float2*)(k1p + 2 * HW + loc) = make_float2(df0, df1);
}

// ---------- K1b: finish stage A ----------
__global__ __launch_bounds__(256) void k_stageA_fin(float* __restrict__ ws, float* __restrict__ dout) {
    int epi = blockIdx.z, img = blockIdx.y;
    int loc = blockIdx.x * 256 + threadIdx.x;
    float ss = 0.f, db = 0.f, df = 0.f;
    for (int cc = 0; cc < 8; ++cc) {
        const float* k1p = ws + OFF_K1P + (((size_t)(epi * 4 + img) * 8 + cc) * 3) * HW + loc;
        ss += k1p[0]; db += k1p[HW]; df += k1p[2 * HW];
    }
    float denom = fmaxf(sqrtf(ss), EPSF);
    float sb = SCL * (db / denom), sf = SCL * (df / denom);
    float m = fmaxf(sb, sf);
    float eb = expf(sb - m), ef = expf(sf - m);
    float s = eb + ef;
    float hb = rintf(eb / s), hf = rintf(ef / s);
    if (img == 0) {
        dout[MASK_OFF + (size_t)(epi * 2) * HW + loc] = hb;
        dout[MASK_OFF + (size_t)(epi * 2 + 1) * HW + loc] = hf;
        ws[OFF_NORMQ + (size_t)epi * HW + loc] = denom;
    } else {
        ws[OFF_WBG + (size_t)(epi * NU + img - 1) * HW + loc] = hb;
        ws[OFF_WFG + (size_t)(epi * NU + img - 1) * HW + loc] = hf;
    }
}

// ---------- K2: initial centroids ----------
__global__ __launch_bounds__(256) void k_initcent(const float* __restrict__ un, float* __restrict__ ws) {
    const int sn[5] = {0, 0, 1, 2, 2};
    const int syo[5] = {0, 71, 47, 23, 95};
    const int sxo[5] = {0, 95, 95, 95, 95};
    int epi = blockIdx.z, j = blockIdx.y;
    int c = blockIdx.x * 256 + threadIdx.x;
    int n = sn[j], yo = syo[j], xo = sxo[j];
    int y0, y1, x0, x1; float wy, wx;
    blc(yo, 47.0 / 95.0, 47, y0, y1, wy);
    blc(xo, 47.0 / 95.0, 47, x0, x1, wx);
    const float* p = un + ((size_t)(epi * NU + n) * NCH + c) * HW;
    float v00 = p[y0 * HH + x0], v10 = p[y1 * HH + x0];
    float v01 = p[y0 * HH + x1], v11 = p[y1 * HH + x1];
    float t0 = v00 * (1.f - wy) + v10 * wy;
    float t1 = v01 * (1.f - wy) + v11 * wy;
    float val = t0 * (1.f - wx) + t1 * wx;
    float* cent = ws + OFF_CENT + (size_t)epi * K10 * NCH;
    cent[(size_t)j * NCH + c] = val;
    cent[(size_t)(j + 5) * NCH + c] = val;
    float* ct = ws + OFF_CT12 + ((size_t)epi * NCH + c) * 12;
    ct[j] = val; ct[j + 5] = val;
}

#define STEP10(A, VX) \
    A[0]=fmaf(VX,ca.x,A[0]); A[1]=fmaf(VX,ca.y,A[1]); A[2]=fmaf(VX,ca.z,A[2]); A[3]=fmaf(VX,ca.w,A[3]); \
    A[4]=fmaf(VX,cb.x,A[4]); A[5]=fmaf(VX,cb.y,A[5]); A[6]=fmaf(VX,cb.z,A[6]); A[7]=fmaf(VX,cb.w,A[7]); \
    A[8]=fmaf(VX,cd.x,A[8]); A[9]=fmaf(VX,cd.y,A[9]);

// ---------- KA: D0 partials, float2 points (8B/lane, 13.5 waves/CU); chains bit-exact ----------
__global__ __launch_bounds__(192) void k_d0part(const float* __restrict__ un, float* __restrict__ ws) {
    int epi = blockIdx.z, cch = blockIdx.y;      // 16 chunks x 128 c
    int c0 = cch * 128;
    int s = (blockIdx.x * 192 + threadIdx.x) * 2;   // 0..6910 (grid.x = 18)
    int n = s / HW, l = s % HW;
    const float* p = un + ((size_t)(epi * NU + n) * NCH + c0) * HW + l;
    const float4* ct = (const float4*)(ws + OFF_CT12 + ((size_t)epi * NCH + c0) * 12);
    float a0[K10], a1[K10];
#pragma unroll
    for (int j = 0; j < K10; ++j) { a0[j] = 0.f; a1[j] = 0.f; }
    for (int cc = 0; cc < 128; ++cc) {
        float2 v = *(const float2*)(p + (size_t)cc * HW);
        float4 ca = ct[cc * 3], cb = ct[cc * 3 + 1], cd = ct[cc * 3 + 2];
        STEP10(a0, v.x) STEP10(a1, v.y)
    }
    float* d0p = ws + OFF_D0P + (size_t)cch * (EPI * K10 * STOT) + (size_t)epi * K10 * STOT;
#pragma unroll
    for (int j = 0; j < K10; ++j)
        *(float2*)(d0p + (size_t)j * STOT + s) = make_float2(a0[j], a1[j]);
}

// ---------- KA2: reduce D0 partials (float4) + c2 ----------
__global__ __launch_bounds__(256) void k_d0red(float* __restrict__ ws) {
    __shared__ float red[256];
    int bid = blockIdx.x;
    if (bid < 270) {
        int idx4 = bid * 256 + threadIdx.x;     // float4 index < 69120
        const float4* src = (const float4*)(ws + OFF_D0P) + idx4;
        float4 a = make_float4(0.f, 0.f, 0.f, 0.f);
        for (int cc = 0; cc < 16; ++cc) {
            float4 v = src[(size_t)cc * 69120];
            a.x += v.x; a.y += v.y; a.z += v.z; a.w += v.w;
        }
        *((float4*)(ws + OFF_D0) + idx4) = a;
    } else {
        int b = bid - 270;                      // epi*10+j
        const float* cent = ws + OFF_CENT + (size_t)b * NCH;
        float ss = 0.f;
        for (int c = threadIdx.x; c < NCH; c += 256) { float v = cent[c]; ss = fmaf(v, v, ss); }
        float tot = blockReduce256(ss, red);
        if (threadIdx.x == 0) ws[OFF_C2 + b] = tot;
    }
}

// ---------- KC: assignments (64-thr blocks spread across all CUs) ----------
__global__ __launch_bounds__(64) void k_assign(const float* __restrict__ ws,
                                               unsigned char* __restrict__ afg,
                                               unsigned char* __restrict__ abg) {
    int epi = blockIdx.y;
    int i = blockIdx.x * 64 + threadIdx.x;      // 0..27647 (grid.x = 432)
    int n = i / UPHW, r = i % UPHW, yo = r / UP, xo = r % UP;
    int y0, y1, x0, x1; float wy, wx;
    blc(yo, 47.0 / 95.0, 47, y0, y1, wy);
    blc(xo, 47.0 / 95.0, 47, x0, x1, wx);
    int sb = n * HW;
    int s00 = sb + y0 * HH + x0, s10 = sb + y1 * HH + x0;
    int s01 = sb + y0 * HH + x1, s11 = sb + y1 * HH + x1;
    const float* D0 = ws + OFF_D0 + (size_t)epi * K10 * STOT;
    const float* c2 = ws + OFF_C2 + epi * K10;
    float dots[K10];
#pragma unroll
    for (int j = 0; j < K10; ++j) {
        const float* dj = D0 + (size_t)j * STOT;
        float t0 = dj[s00] * (1.f - wy) + dj[s10] * wy;
        float t1 = dj[s01] * (1.f - wy) + dj[s11] * wy;
        dots[j] = t0 * (1.f - wx) + t1 * wx;
    }
    int bf = 0; float best = fmaf(-2.f, dots[0], c2[0]);
#pragma unroll
    for (int j = 1; j < 5; ++j) { float sc = fmaf(-2.f, dots[j], c2[j]); if (sc < best) { best = sc; bf = j; } }
    int bb = 0; best = fmaf(-2.f, dots[5], c2[5]);
#pragma unroll
    for (int j = 1; j < 5; ++j) { float sc = fmaf(-2.f, dots[5 + j], c2[5 + j]); if (sc < best) { best = sc; bb = j; } }
    afg[(size_t)epi * UPS + i] = (unsigned char)bf;
    abg[(size_t)epi * UPS + i] = (unsigned char)bb;
}

// ---------- KD: gather A^T rows via precomputed table (register-resident, bit-exact) ----------
__global__ __launch_bounds__(256) void k_gatherA(float* __restrict__ ws,
                                                 const unsigned char* __restrict__ afg,
                                                 const unsigned char* __restrict__ abg) {
    __shared__ float red2[10][256];
    int epi = blockIdx.y;
    int s = blockIdx.x * 256 + threadIdx.x;     // 0..6911
    int n = s / HW, loc = s % HW, y = loc / HH, x = loc % HH;

    const float2* tab = (const float2*)(ws + OFF_BTAB);
    float2 ty[6], tx[6];
#pragma unroll
    for (int t = 0; t < 6; ++t) { ty[t] = tab[y * 6 + t]; tx[t] = tab[x * 6 + t]; }

    float Af[5] = {0, 0, 0, 0, 0}, Ab[5] = {0, 0, 0, 0, 0};
    const unsigned char* fa = afg + (size_t)epi * UPS;
    const unsigned char* ba = abg + (size_t)epi * UPS;
    const float* WF = ws + OFF_WFG + (size_t)(epi * NU + n) * HW;
    const float* WB = ws + OFF_WBG + (size_t)(epi * NU + n) * HW;
#pragma unroll
    for (int a = 0; a < 6; ++a) {
#pragma unroll
        for (int b = 0; b < 6; ++b) {
            int yo = (int)ty[a].x, xo = (int)tx[b].x;
            int i = n * UPHW + yo * UP + xo;
            float coef = ty[a].y * tx[b].y;
            int mi = (yo >> 1) * HH + (xo >> 1);
            float cf = coef * WF[mi], cb = coef * WB[mi];
            int jf = fa[i], jb = ba[i];
#pragma unroll
            for (int j = 0; j < 5; ++j) {
                Af[j] += (jf == j) ? cf : 0.f;
                Ab[j] += (jb == j) ? cb : 0.f;
            }
        }
    }
    float* at = ws + OFF_AT12 + ((size_t)epi * STOT + s) * 12;
#pragma unroll
    for (int j = 0; j < 5; ++j) { at[j] = Af[j]; at[5 + j] = Ab[j]; }
    // block-partial dens (fg j=0..4, bg j=5..9)
    int t = threadIdx.x;
#pragma unroll
    for (int j = 0; j < 5; ++j) { red2[j][t] = Af[j]; red2[5 + j][t] = Ab[j]; }
    __syncthreads();
    for (int st = 128; st > 0; st >>= 1) {
        for (int e = t; e < 10 * st; e += 256) {
            int j = e / st, i2 = e % st;
            red2[j][i2] += red2[j][i2 + st];
        }
        __syncthreads();
    }
    if (t < 10) ws[OFF_DENP + ((size_t)epi * 27 + blockIdx.x) * 10 + t] = red2[t][0];
}

// ---------- KF: num partials, LDS-tiled transpose-consume ----------
__global__ __launch_bounds__(256) void k_numpart(const float* __restrict__ un, float* __restrict__ ws) {
    __shared__ float tile[STILE * LDSROW];      // 16 x 257 floats = 16.4 KB
    int epi = blockIdx.z;
    int strip = blockIdx.y;                     // 0..47
    int c0 = blockIdx.x * 256;                  // 8 chunks
    int n = strip >> 4;
    int loc0 = (strip & 15) * SSTRIP;
    int t = threadIdx.x;
    int cl = t >> 2;                            // 0..63
    int si0 = (t & 3) * 4;                      // 0,4,8,12
    float acc[K10];
#pragma unroll
    for (int j = 0; j < K10; ++j) acc[j] = 0.f;
    const float* ubase = un + ((size_t)(epi * NU + n) * NCH + c0) * HW + loc0;
    const float* atbase = ws + OFF_AT12 + ((size_t)epi * STOT + n * HW + loc0) * 12;
    for (int tt = 0; tt < SSTRIP / STILE; ++tt) {
#pragma unroll
        for (int pass = 0; pass < 4; ++pass) {
            int c = cl + 64 * pass;
            float4 v = *(const float4*)(ubase + (size_t)c * HW + tt * STILE + si0);
            tile[(si0 + 0) * LDSROW + c] = v.x;
            tile[(si0 + 1) * LDSROW + c] = v.y;
            tile[(si0 + 2) * LDSROW + c] = v.z;
            tile[(si0 + 3) * LDSROW + c] = v.w;
        }
        __syncthreads();
#pragma unroll
        for (int si = 0; si < STILE; ++si) {
            float x = tile[si * LDSROW + t];
            const float* at = atbase + (size_t)(tt * STILE + si) * 12;
#pragma unroll
            for (int j = 0; j < K10; ++j) acc[j] = fmaf(x, at[j], acc[j]);
        }
        __syncthreads();
    }
    float* np = ws + OFF_NUMP + ((size_t)(epi * NSTRIPS + strip) * K10) * NCH + c0 + t;
#pragma unroll
    for (int j = 0; j < K10; ++j) np[(size_t)j * NCH] = acc[j];
}

// ---------- KF2: centroid update (den finish + CT12 write) ----------
__global__ __launch_bounds__(256) void k_centup(float* __restrict__ ws) {
    __shared__ float sden;
    int idx = blockIdx.x * 256 + threadIdx.x;   // < 81920
    int epi = idx / (K10 * NCH);
    int r = idx - epi * K10 * NCH;
    int j = r >> 11, c = r & 2047;
    if (threadIdx.x == 0) {
        float d = 0.f;
        for (int b = 0; b < 27; ++b) d += ws[OFF_DENP + ((size_t)epi * 27 + b) * 10 + j];
        sden = d;
    }
    __syncthreads();
    float num = 0.f;
#pragma unroll 8
    for (int sc = 0; sc < NSTRIPS; ++sc)
        num += ws[OFF_NUMP + ((size_t)(epi * NSTRIPS + sc) * K10 + j) * NCH + c];
    float d = sden;
    size_t ci = OFF_CENT + ((size_t)epi * K10 + j) * NCH + c;
    float newv = (d > 0.f) ? num / (d + EPSF) : ws[ci];
    ws[ci] = newv;
    ws[OFF_CT12 + ((size_t)epi * NCH + c) * 12 + j] = newv;
}

// ---------- KG: build normalized 12-proto interleaved matrix ----------
__global__ __launch_bounds__(256) void k_buildP12(float* __restrict__ ws) {
    __shared__ float red[256];
    int b = blockIdx.x;                        // epi*12+r
    int epi = b / 12, r = b % 12;
    const float* src;
    bool copy = false;
    if (r == 0)      { src = ws + OFF_PNBG + (size_t)epi * NCH; copy = true; }
    else if (r < 6)  { src = ws + OFF_CENT + ((size_t)epi * K10 + 4 + r) * NCH; }   // bg_cls j=5..9
    else if (r == 6) { src = ws + OFF_PNFG + (size_t)epi * NCH; copy = true; }
    else             { src = ws + OFF_CENT + ((size_t)epi * K10 + r - 7) * NCH; }   // fg_cls j=0..4
    float denom = 1.f;
    if (!copy) {
        float ss = 0.f;
        for (int c = threadIdx.x; c < NCH; c += 256) { float v = src[c]; ss = fmaf(v, v, ss); }
        float tot = blockReduce256(ss, red);
        denom = fmaxf(sqrtf(tot), EPSF);
    }
    for (int c = threadIdx.x; c < NCH; c += 256)
        ws[OFF_P12 + ((size_t)epi * NCH + c) * 12 + r] = src[c] / denom;
}

#define STEP12(A, VX) \
    A[0]=fmaf(VX,pa.x,A[0]); A[1]=fmaf(VX,pa.y,A[1]); A[2]=fmaf(VX,pa.z,A[2]); A[3]=fmaf(VX,pa.w,A[3]); \
    A[4]=fmaf(VX,pb.x,A[4]); A[5]=fmaf(VX,pb.y,A[5]); A[6]=fmaf(VX,pb.z,A[6]); A[7]=fmaf(VX,pb.w,A[7]); \
    A[8]=fmaf(VX,pc.x,A[8]); A[9]=fmaf(VX,pc.y,A[9]); A[10]=fmaf(VX,pc.z,A[10]); A[11]=fmaf(VX,pc.w,A[11]);

// ---------- KHa: final sims vs 12 protos, 64-ch chunks x float2 (8B/lane) ----------
__global__ __launch_bounds__(192) void k_pred_part(const float* __restrict__ qft, float* __restrict__ ws) {
    int epi = blockIdx.z, cc = blockIdx.y;      // 0..31, 64 channels each
    int c0 = cc * 64;
    int loc = (blockIdx.x * 192 + threadIdx.x) * 2;   // 0..2302 (grid.x = 6)
    const float* q = qft + ((size_t)epi * NCH + c0) * HW + loc;
    const float4* pr = (const float4*)(ws + OFF_P12 + ((size_t)epi * NCH + c0) * 12);
    float a0[12], a1[12];
#pragma unroll
    for (int r = 0; r < 12; ++r) { a0[r] = 0.f; a1[r] = 0.f; }
    for (int i = 0; i < 64; ++i) {
        float2 v = *(const float2*)(q + (size_t)i * HW);
        float4 pa = pr[i * 3], pb = pr[i * 3 + 1], pc = pr[i * 3 + 2];
        STEP12(a0, v.x) STEP12(a1, v.y)
    }
    float* khp = ws + OFF_KHP + ((size_t)(epi * 32 + cc) * 12) * HW;
#pragma unroll
    for (int r = 0; r < 12; ++r)
        *(float2*)(khp + (size_t)r * HW + loc) = make_float2(a0[r], a1[r]);
}

// ---------- KHb: reduce 32 chunks, max over protos, softmax ----------
__global__ __launch_bounds__(256) void k_pred_fin(float* __restrict__ ws) {
    int epi = blockIdx.y;
    int loc = blockIdx.x * 256 + threadIdx.x;
    float dot[12];
#pragma unroll
    for (int r = 0; r < 12; ++r) dot[r] = 0.f;
    for (int cc = 0; cc < 32; ++cc) {
        const float* khp = ws + OFF_KHP + ((size_t)(epi * 32 + cc) * 12) * HW + loc;
#pragma unroll
        for (int r = 0; r < 12; ++r) dot[r] += khp[(size_t)r * HW];
    }
    float mb = dot[0];
#pragma unroll
    for (int r = 1; r < 6; ++r) mb = fmaxf(mb, dot[r]);
    float mf = dot[6];
#pragma unroll
    for (int r = 7; r < 12; ++r) mf = fmaxf(mf, dot[r]);
    float denom = ws[OFF_NORMQ + (size_t)epi * HW + loc];
    float sb = SCL * (mb / denom), sf = SCL * (mf / denom);
    float m = fmaxf(sb, sf);
    float eb = expf(sb - m), ef = expf(sf - m);
    float ssum = eb + ef;
    ws[OFF_OUTS + (size_t)(epi * 2) * HW + loc] = eb / ssum;
    ws[OFF_OUTS + (size_t)(epi * 2 + 1) * HW + loc] = ef / ssum;
}

// ---------- KI: bilinear resize 48x48 -> 417x417 ----------
__global__ __launch_bounds__(256) void k_resize(const float* __restrict__ ws, float* __restrict__ dout) {
    int idx = blockIdx.x * 256 + threadIdx.x;
    if (idx >= 8 * OUTHW) return;
    int img = idx / OUTHW, r = idx - img * OUTHW;
    int yo = r / OUTD, xo = r - yo * OUTD;
    int y0, y1, x0, x1; float wy, wx;
    blc(yo, 47.0 / 416.0, 47, y0, y1, wy);
    blc(xo, 47.0 / 416.0, 47, x0, x1, wx);
    const float* src = ws + OFF_OUTS + (size_t)img * HW;
    float t0 = src[y0 * HH + x0] * (1.f - wy) + src[y1 * HH + x0] * wy;
    float t1 = src[y0 * HH + x1] * (1.f - wy) + src[y1 * HH + x1] * wy;
    dout[idx] = t0 * (1.f - wx) + t1 * wx;
}

extern "C" void kernel_launch(void* const* d_in, const int* in_sizes, int n_in,
                              void* d_out, int out_size, void* d_ws, size_t ws_size,
                              hipStream_t stream) {
    const float* sprotos = (const float*)d_in[0];
    const float* qft     = (const float*)d_in[1];
    const float* un      = (const float*)d_in[2];
    float* ws  = (float*)d_ws;
    float* out = (float*)d_out;
    unsigned char* afg = (unsigned char*)d_ws + ASSIGN_BYTE_OFF;
    unsigned char* abg = afg + (size_t)EPI * UPS;

    hipLaunchKernelGGL(k_protonorm, dim3(8), dim3(256), 0, stream, sprotos, ws);
    hipLaunchKernelGGL(k_btab, dim3(1), dim3(64), 0, stream, ws);
    hipLaunchKernelGGL(k_stageA_part, dim3(6, 32, EPI), dim3(192), 0, stream, qft, un, ws);
    hipLaunchKernelGGL(k_stageA_fin, dim3(9, 4, EPI), dim3(256), 0, stream, ws, out);
    hipLaunchKernelGGL(k_initcent, dim3(8, 5, EPI), dim3(256), 0, stream, un, ws);
    for (int it = 0; it < KM_IT; ++it) {
        hipLaunchKernelGGL(k_d0part, dim3(18, 16, EPI), dim3(192), 0, stream, un, ws);
        hipLaunchKernelGGL(k_d0red, dim3(310), dim3(256), 0, stream, ws);
        hipLaunchKernelGGL(k_assign, dim3(432, EPI), dim3(64), 0, stream, ws, afg, abg);
        hipLaunchKernelGGL(k_gatherA, dim3(27, EPI), dim3(256), 0, stream, ws, afg, abg);
        hipLaunchKernelGGL(k_numpart, dim3(8, NSTRIPS, EPI), dim3(256), 0, stream, un, ws);
        hipLaunchKernelGGL(k_centup, dim3(320), dim3(256), 0, stream, ws);
    }
    hipLaunchKernelGGL(k_buildP12, dim3(48), dim3(256), 0, stream, ws);
    hipLaunchKernelGGL(k_pred_part, dim3(6, 32, EPI), dim3(192), 0, stream, qft, ws);
    hipLaunchKernelGGL(k_pred_fin, dim3(9, EPI), dim3(256), 0, stream, ws);
    hipLaunchKernelGGL(k_resize, dim3(5435), dim3(256), 0, stream, ws, out);
}